// Round 12
// baseline (580.419 us; speedup 1.0000x reference)
//
#include <hip/hip_runtime.h>
#include <hip/hip_fp16.h>

#define NN 50000
#define NE 800000
#define HH 128
#define SCAN_BS 512
#define SCAN_NB 98
#define LDK 40
#define LDA 136
#define LDU 264
#define EBLK ((NE + 255) / 256)   // 3125

typedef _Float16 half8 __attribute__((ext_vector_type(8)));
typedef float f32x4  __attribute__((ext_vector_type(4)));

// ---------------------------------------------------------------------------
// prep: blocks [0,480) transpose+cast weights; blocks [480, 480+EBLK) histogram.
// ---------------------------------------------------------------------------
__global__ __launch_bounds__(256)
void prep_kernel(const float* __restrict__ s0,  const float* __restrict__ s1,
                 const float* __restrict__ s2,  const float* __restrict__ s3,
                 const float* __restrict__ s4,  const float* __restrict__ s5,
                 const float* __restrict__ s6,  const float* __restrict__ s7,
                 const float* __restrict__ s8,  const float* __restrict__ s9,
                 const float* __restrict__ s10, const float* __restrict__ s11,
                 const float* __restrict__ s12, const float* __restrict__ s13,
                 const float* __restrict__ s14, _Float16* __restrict__ wps,
                 const int* __restrict__ ei, int* __restrict__ deg)
{
    const int b = blockIdx.x;
    if (b >= 480) {
        const int e = (b - 480) * 256 + threadIdx.x;
        if (e < NE) atomicAdd(&deg[ei[NE + e]], 1);
        return;
    }
    const float* srcs[15] = {s0,s1,s2,s3,s4,s5,s6,s7,s8,s9,s10,s11,s12,s13,s14};
    const int Ks[15]   = {64,128,128,128,128,128,128,128,128,128,128,128,128,128,256};
    const int logKs[15]= { 6,  7,  7,  7,  7,  7,  7,  7,  7,  7,  7,  7,  7,  7,  8};
    const int off[15]  = {0,8192,24576,40960,57344,73728,90112,106496,122880,
                          139264,155648,172032,188416,204800,237568};

    const int mi = b >> 5;
    const int bx = b & 31;
    const float* src = srcs[mi];
    const int K = Ks[mi], logK = logKs[mi];
    const int N = (mi == 13) ? 256 : 128;
    _Float16* dst = wps + off[mi];
    const int tot = K * N;
    const int base = (bx * 256 + threadIdx.x) * 4;
    if (base >= tot) return;
    const int n = base >> logK;
    const int k = base & (K - 1);
#pragma unroll
    for (int x = 0; x < 4; ++x)
        dst[(size_t)n * K + k + x] = (_Float16)src[(size_t)(k + x) * N + n];
}

// ---------------------------------------------------------------------------
// LDS->LDS layer (256-thread kernels)
// ---------------------------------------------------------------------------
template<bool RELU>
__device__ __forceinline__ void layer_l2l(
    const _Float16* __restrict__ actA, int lda, int K,
    const _Float16* __restrict__ Bt,
    const float* __restrict__ bias,
    _Float16* __restrict__ actO, int ldo, int oc0,
    _Float16* __restrict__ Bs)
{
    const int t = threadIdx.x, lane = t & 63;
    const int wr = (t >> 6) >> 1, wc = (t >> 6) & 1;
    const int fr = lane & 15, fg = lane >> 4;
    const int rb = t >> 1, kb = (t & 1) * 16;

    f32x4 acc[2][4] = {};
    for (int k0 = 0; k0 < K; k0 += 32) {
        const _Float16* p = Bt + (size_t)rb * K + k0 + kb;
        const half8 v0 = *reinterpret_cast<const half8*>(p);
        const half8 v1 = *reinterpret_cast<const half8*>(p + 8);
        *reinterpret_cast<half8*>(&Bs[rb * LDK + kb])     = v0;
        *reinterpret_cast<half8*>(&Bs[rb * LDK + kb + 8]) = v1;
        __syncthreads();

        half8 a[2], bfr[4];
#pragma unroll
        for (int i = 0; i < 2; ++i)
            a[i] = *reinterpret_cast<const half8*>(&actA[(wr * 32 + i * 16 + fr) * lda + k0 + fg * 8]);
#pragma unroll
        for (int j = 0; j < 4; ++j)
            bfr[j] = *reinterpret_cast<const half8*>(&Bs[(wc * 64 + j * 16 + fr) * LDK + fg * 8]);
#pragma unroll
        for (int i = 0; i < 2; ++i)
#pragma unroll
            for (int j = 0; j < 4; ++j)
                acc[i][j] = __builtin_amdgcn_mfma_f32_16x16x32_f16(a[i], bfr[j], acc[i][j], 0, 0, 0);
        __syncthreads();
    }
#pragma unroll
    for (int j = 0; j < 4; ++j) {
        const int gnl = wc * 64 + j * 16 + fr;
        const float bv = bias[gnl];
#pragma unroll
        for (int i = 0; i < 2; ++i)
#pragma unroll
            for (int rr = 0; rr < 4; ++rr) {
                float v = acc[i][j][rr] + bv;
                if (RELU) v = fmaxf(v, 0.f);
                actO[(wr * 32 + i * 16 + fg * 4 + rr) * ldo + oc0 + gnl] = (_Float16)v;
            }
    }
    __syncthreads();
}

// ---------------------------------------------------------------------------
// phase5: blocks [0,EBLK) scatter + CSR-ordered ea2; rest run fused node MLP.
// ---------------------------------------------------------------------------
__global__ __launch_bounds__(256)
void phase5_kernel(const int* __restrict__ ei, const int* __restrict__ offs,
                   int* __restrict__ cur, const float* __restrict__ ea,
                   int* __restrict__ csr_src, unsigned* __restrict__ ea2,
                   const float* __restrict__ G,
                   const _Float16* __restrict__ W1, const float* __restrict__ b1,
                   const _Float16* __restrict__ W2, const float* __restrict__ b2,
                   const _Float16* __restrict__ W3, const float* __restrict__ b3,
                   _Float16* __restrict__ outf, int M)
{
    __shared__ __attribute__((aligned(16))) _Float16 AA[64 * LDA];
    __shared__ __attribute__((aligned(16))) _Float16 AB[64 * LDA];
    __shared__ __attribute__((aligned(16))) _Float16 Bs[128 * LDK];

    const int t = threadIdx.x;
    if (blockIdx.x < EBLK) {
        const int e = blockIdx.x * 256 + t;
        if (e >= NE) return;
        const int d = ei[NE + e];
        const int p = offs[d] + atomicAdd(&cur[d], 1);
        csr_src[p] = ei[e];
        const float* src = ea + (size_t)e * 21;
        unsigned* dst = ea2 + (size_t)p * 21;
#pragma unroll
        for (int q = 0; q < 21; ++q) {
            const __half2 h = __floats2half2_rn(src[q], src[q]);
            dst[q] = __builtin_bit_cast(unsigned, h);
        }
        return;
    }

    const int m0 = (blockIdx.x - EBLK) << 6;
    {
        const int r  = t >> 2;
        const int c0 = (t & 3) * 16;
        const int gm = m0 + r;
#pragma unroll
        for (int h = 0; h < 2; ++h) {
            float4 v0 = make_float4(0.f, 0.f, 0.f, 0.f), v1 = v0;
            if (gm < M) {
                v0 = *reinterpret_cast<const float4*>(G + (size_t)gm * 64 + c0 + h * 8);
                v1 = *reinterpret_cast<const float4*>(G + (size_t)gm * 64 + c0 + h * 8 + 4);
            }
            half8 hv;
            hv[0] = (_Float16)v0.x; hv[1] = (_Float16)v0.y;
            hv[2] = (_Float16)v0.z; hv[3] = (_Float16)v0.w;
            hv[4] = (_Float16)v1.x; hv[5] = (_Float16)v1.y;
            hv[6] = (_Float16)v1.z; hv[7] = (_Float16)v1.w;
            *reinterpret_cast<half8*>(&AA[r * LDA + c0 + h * 8]) = hv;
        }
    }
    __syncthreads();

    layer_l2l<true>(AA, LDA, 64,  W1, b1, AB, LDA, 0, Bs);
    layer_l2l<true>(AB, LDA, 128, W2, b2, AA, LDA, 0, Bs);
    layer_l2l<true>(AA, LDA, 128, W3, b3, AB, LDA, 0, Bs);

    {
        const int r  = t >> 2;
        const int c0 = (t & 3) * 32;
        const int gm = m0 + r;
        if (gm < M) {
#pragma unroll
            for (int x = 0; x < 32; x += 8)
                *reinterpret_cast<half8*>(outf + (size_t)gm * 128 + c0 + x) =
                    *reinterpret_cast<const half8*>(&AB[r * LDA + c0 + x]);
        }
    }
}

// ---------------------------------------------------------------------------
// kqvs v2: one 64x512 GEMM per block. 512 threads = 8 waves; wave (wr, wc)
// covers 32 rows x 128 cols; wc selects the weight set {k', s, q', v}.
// ---------------------------------------------------------------------------
__global__ __launch_bounds__(512)
void kqvs_kernel(const _Float16* __restrict__ act,
                 const _Float16* __restrict__ B0, const _Float16* __restrict__ B1,
                 const _Float16* __restrict__ B2, const _Float16* __restrict__ B3,
                 const float* __restrict__ b0, const float* __restrict__ b1,
                 const float* __restrict__ b2, const float* __restrict__ b3,
                 _Float16* __restrict__ ksb, _Float16* __restrict__ qvb, int M)
{
    __shared__ __attribute__((aligned(16))) _Float16 AA[64 * LDA];    // 17.4 KB
    __shared__ __attribute__((aligned(16))) _Float16 Bs[512 * LDK];   // 41 KB

    const int t    = threadIdx.x, lane = t & 63;
    const int wid  = t >> 6;                  // 0..7
    const int wr   = wid >> 2;                // rows half
    const int wc   = wid & 3;                 // weight set
    const int fr   = lane & 15, fg = lane >> 4;
    const int m0   = blockIdx.x << 6;

    // stage activations 64x128
    {
        const int r  = t >> 3;
        const int c0 = (t & 7) * 16;
        const int gm = m0 + r;
        half8 v0 = {0,0,0,0,0,0,0,0}, v1 = v0;
        if (gm < M) {
            v0 = *reinterpret_cast<const half8*>(act + (size_t)gm * 128 + c0);
            v1 = *reinterpret_cast<const half8*>(act + (size_t)gm * 128 + c0 + 8);
        }
        *reinterpret_cast<half8*>(&AA[r * LDA + c0])     = v0;
        *reinterpret_cast<half8*>(&AA[r * LDA + c0 + 8]) = v1;
    }

    // weight stage source: thread t owns Bs row t (set = t>>7, row-in-set = t&127)
    const _Float16* Bt_stage = (t < 128) ? B0 : (t < 256) ? B1 : (t < 384) ? B2 : B3;
    const _Float16* srow = Bt_stage + (size_t)(t & 127) * 128;

    __syncthreads();

    f32x4 acc[2][8] = {};
    for (int k0 = 0; k0 < 128; k0 += 32) {
        {
            const half8 v0 = *reinterpret_cast<const half8*>(srow + k0);
            const half8 v1 = *reinterpret_cast<const half8*>(srow + k0 + 8);
            const half8 v2 = *reinterpret_cast<const half8*>(srow + k0 + 16);
            const half8 v3 = *reinterpret_cast<const half8*>(srow + k0 + 24);
            *reinterpret_cast<half8*>(&Bs[t * LDK + 0])  = v0;
            *reinterpret_cast<half8*>(&Bs[t * LDK + 8])  = v1;
            *reinterpret_cast<half8*>(&Bs[t * LDK + 16]) = v2;
            *reinterpret_cast<half8*>(&Bs[t * LDK + 24]) = v3;
        }
        __syncthreads();

        half8 a[2], b[8];
#pragma unroll
        for (int i = 0; i < 2; ++i)
            a[i] = *reinterpret_cast<const half8*>(&AA[(wr * 32 + i * 16 + fr) * LDA + k0 + fg * 8]);
#pragma unroll
        for (int j = 0; j < 8; ++j)
            b[j] = *reinterpret_cast<const half8*>(&Bs[(wc * 128 + j * 16 + fr) * LDK + fg * 8]);
#pragma unroll
        for (int i = 0; i < 2; ++i)
#pragma unroll
            for (int j = 0; j < 8; ++j)
                acc[i][j] = __builtin_amdgcn_mfma_f32_16x16x32_f16(a[i], b[j], acc[i][j], 0, 0, 0);
        __syncthreads();
    }

    // epilogue: wave's set = wc
    _Float16* dst  = (wc < 2) ? ksb : qvb;
    const int  sub = (wc & 1) * 2;
    const float scl = (wc == 0 || wc == 2) ? -1.44269504f : 1.0f;   // k', q'
    const float* bt = (wc == 0) ? b0 : (wc == 1) ? b1 : (wc == 2) ? b2 : b3;
#pragma unroll
    for (int j = 0; j < 8; ++j) {
        const int gnl = j * 16 + fr;
        const int pos = ((gnl >> 1) << 2) + sub + (gnl & 1);
        const float bv = bt[gnl];
#pragma unroll
        for (int i = 0; i < 2; ++i) {
            const int mbase = m0 + wr * 32 + i * 16 + fg * 4;
#pragma unroll
            for (int rr = 0; rr < 4; ++rr) {
                const int gm = mbase + rr;
                if (gm < M)
                    dst[(size_t)gm * 256 + pos] = (_Float16)((acc[i][j][rr] + bv) * scl);
            }
        }
    }
}

// ---------------------------------------------------------------------------
// Fused graph MLP (+colsum) with last-block gvec computation.
// ---------------------------------------------------------------------------
__global__ __launch_bounds__(256)
void graph2_kernel(const _Float16* __restrict__ act,
                   const _Float16* __restrict__ Wg1t, const float* __restrict__ bg1,
                   const _Float16* __restrict__ Wg2t, const float* __restrict__ bg2,
                   _Float16* __restrict__ g2f, float* __restrict__ gsum,
                   const float* __restrict__ Wl1, const float* __restrict__ bl1,
                   float* __restrict__ gvec, int* __restrict__ cnt,
                   float invM, int M)
{
    __shared__ __attribute__((aligned(16))) _Float16 AA[64 * LDA];
    __shared__ __attribute__((aligned(16))) _Float16 AB[64 * LDA];
    __shared__ __attribute__((aligned(16))) _Float16 Bs[128 * LDK];

    const int t  = threadIdx.x, lane = t & 63;
    const int m0 = blockIdx.x << 6;
    const int wr = (t >> 6) >> 1, wc = (t >> 6) & 1;
    const int fr = lane & 15, fg = lane >> 4;
    const int rb = t >> 1, kb = (t & 1) * 16;

    {
        const int r  = t >> 2;
        const int c0 = (t & 3) * 32;
        const int gm = m0 + r;
#pragma unroll
        for (int x = 0; x < 32; x += 8) {
            half8 v = {0,0,0,0,0,0,0,0};
            if (gm < M) v = *reinterpret_cast<const half8*>(act + (size_t)gm * 128 + c0 + x);
            *reinterpret_cast<half8*>(&AA[r * LDA + c0 + x]) = v;
        }
    }
    __syncthreads();

    layer_l2l<true>(AA, LDA, 128, Wg1t, bg1, AB, LDA, 0, Bs);

    f32x4 acc[2][4] = {};
    for (int k0 = 0; k0 < 128; k0 += 32) {
        const _Float16* p = Wg2t + (size_t)rb * 128 + k0 + kb;
        const half8 v0 = *reinterpret_cast<const half8*>(p);
        const half8 v1 = *reinterpret_cast<const half8*>(p + 8);
        *reinterpret_cast<half8*>(&Bs[rb * LDK + kb])     = v0;
        *reinterpret_cast<half8*>(&Bs[rb * LDK + kb + 8]) = v1;
        __syncthreads();
        half8 a[2], b[4];
#pragma unroll
        for (int i = 0; i < 2; ++i)
            a[i] = *reinterpret_cast<const half8*>(&AB[(wr * 32 + i * 16 + fr) * LDA + k0 + fg * 8]);
#pragma unroll
        for (int j = 0; j < 4; ++j)
            b[j] = *reinterpret_cast<const half8*>(&Bs[(wc * 64 + j * 16 + fr) * LDK + fg * 8]);
#pragma unroll
        for (int i = 0; i < 2; ++i)
#pragma unroll
            for (int j = 0; j < 4; ++j)
                acc[i][j] = __builtin_amdgcn_mfma_f32_16x16x32_f16(a[i], b[j], acc[i][j], 0, 0, 0);
        __syncthreads();
    }
#pragma unroll
    for (int j = 0; j < 4; ++j) {
        const int gn = wc * 64 + j * 16 + fr;
        const float bv = bg2[gn];
        float csum = 0.f;
#pragma unroll
        for (int i = 0; i < 2; ++i) {
            const int mbase = m0 + wr * 32 + i * 16 + fg * 4;
#pragma unroll
            for (int rr = 0; rr < 4; ++rr) {
                const int gm = mbase + rr;
                if (gm < M) {
                    const float v = acc[i][j][rr] + bv;
                    csum += v;
                    g2f[(size_t)gm * 128 + gn] = (_Float16)v;
                }
            }
        }
        csum += __shfl_xor(csum, 16);
        csum += __shfl_xor(csum, 32);
        if (fg == 0) atomicAdd(&gsum[gn], csum);
    }

    // ---- last-block: compute gvec = bl1 + (gsum/M) @ Wl1[128:256,:]
    __shared__ int lastFlag;
    __shared__ float gs[128];
    __threadfence();
    if (t == 0) lastFlag = (atomicAdd(cnt, 1) == (int)gridDim.x - 1) ? 1 : 0;
    __syncthreads();
    if (lastFlag) {
        if (t < 128) gs[t] = atomicAdd(&gsum[t], 0.f) * invM;   // coherent read
        __syncthreads();
        float accv = bl1[t];
        for (int k = 0; k < 128; ++k)
            accv += gs[k] * Wl1[(size_t)(128 + k) * 256 + t];
        gvec[t] = accv;
    }
}

// ---------------------------------------------------------------------------
// Fused head (unchanged)
// ---------------------------------------------------------------------------
__global__ __launch_bounds__(256)
void head3_kernel(const _Float16* __restrict__ g2f,
                  const _Float16* __restrict__ Wl1t,
                  const float* __restrict__ gvec,
                  const _Float16* __restrict__ Wl2t,
                  const float* __restrict__ bl2,
                  const float* __restrict__ wl3,
                  const float* __restrict__ bl3,
                  float* __restrict__ out, int M)
{
    __shared__ __attribute__((aligned(16))) _Float16 AA[64 * LDA];
    __shared__ __attribute__((aligned(16))) _Float16 UB[64 * LDU];
    __shared__ __attribute__((aligned(16))) _Float16 Bs[128 * LDK];
    __shared__ float psum[2][64];

    const int t  = threadIdx.x, lane = t & 63;
    const int m0 = blockIdx.x << 6;
    const int wr = (t >> 6) >> 1, wc = (t >> 6) & 1;
    const int fr = lane & 15, fg = lane >> 4;
    const int rb = t >> 1, kb = (t & 1) * 16;

    {
        const int r  = t >> 2;
        const int c0 = (t & 3) * 32;
        const int gm = m0 + r;
#pragma unroll
        for (int x = 0; x < 32; x += 8) {
            half8 v = {0,0,0,0,0,0,0,0};
            if (gm < M) v = *reinterpret_cast<const half8*>(g2f + (size_t)gm * 128 + c0 + x);
            *reinterpret_cast<half8*>(&AA[r * LDA + c0 + x]) = v;
        }
    }
    __syncthreads();

    layer_l2l<true>(AA, LDA, 128, Wl1t,             gvec,       UB, LDU, 0,   Bs);
    layer_l2l<true>(AA, LDA, 128, Wl1t + 128 * 128, gvec + 128, UB, LDU, 128, Bs);

    f32x4 acc[2][4] = {};
    for (int k0 = 0; k0 < 256; k0 += 32) {
        const _Float16* p = Wl2t + (size_t)rb * 256 + k0 + kb;
        const half8 v0 = *reinterpret_cast<const half8*>(p);
        const half8 v1 = *reinterpret_cast<const half8*>(p + 8);
        *reinterpret_cast<half8*>(&Bs[rb * LDK + kb])     = v0;
        *reinterpret_cast<half8*>(&Bs[rb * LDK + kb + 8]) = v1;
        __syncthreads();
        half8 a[2], b[4];
#pragma unroll
        for (int i = 0; i < 2; ++i)
            a[i] = *reinterpret_cast<const half8*>(&UB[(wr * 32 + i * 16 + fr) * LDU + k0 + fg * 8]);
#pragma unroll
        for (int j = 0; j < 4; ++j)
            b[j] = *reinterpret_cast<const half8*>(&Bs[(wc * 64 + j * 16 + fr) * LDK + fg * 8]);
#pragma unroll
        for (int i = 0; i < 2; ++i)
#pragma unroll
            for (int j = 0; j < 4; ++j)
                acc[i][j] = __builtin_amdgcn_mfma_f32_16x16x32_f16(a[i], b[j], acc[i][j], 0, 0, 0);
        __syncthreads();
    }

    float p[2][4] = {};
#pragma unroll
    for (int j = 0; j < 4; ++j) {
        const int gnl = wc * 64 + j * 16 + fr;
        const float bv = bl2[gnl];
        const float wv = wl3[gnl];
#pragma unroll
        for (int i = 0; i < 2; ++i)
#pragma unroll
            for (int rr = 0; rr < 4; ++rr)
                p[i][rr] += fmaxf(acc[i][j][rr] + bv, 0.f) * wv;
    }
#pragma unroll
    for (int i = 0; i < 2; ++i)
#pragma unroll
        for (int rr = 0; rr < 4; ++rr) {
            float s = p[i][rr];
            s += __shfl_xor(s, 1);
            s += __shfl_xor(s, 2);
            s += __shfl_xor(s, 4);
            s += __shfl_xor(s, 8);
            p[i][rr] = s;
        }
    if (fr == 0) {
#pragma unroll
        for (int i = 0; i < 2; ++i)
#pragma unroll
            for (int rr = 0; rr < 4; ++rr)
                psum[wc][wr * 32 + i * 16 + fg * 4 + rr] = p[i][rr];
    }
    __syncthreads();
    if (t < 64) {
        const int gm = m0 + t;
        if (gm < M) out[gm] = psum[0][t] + psum[1][t] + bl3[0];
    }
}

// ---------------------------------------------------------------------------
// scan1 with fused scan2 (last-block exclusive scan of block sums)
// ---------------------------------------------------------------------------
__global__ __launch_bounds__(SCAN_BS)
void scan1_kernel(const int* __restrict__ deg, int* __restrict__ incl,
                  int* __restrict__ bsum, int* __restrict__ cnt)
{
    __shared__ int sm[SCAN_BS];
    const int t = threadIdx.x;
    const int i = blockIdx.x * SCAN_BS + t;
    sm[t] = (i < NN) ? deg[i] : 0;
    __syncthreads();
    for (int d = 1; d < SCAN_BS; d <<= 1) {
        const int add = (t >= d) ? sm[t - d] : 0;
        __syncthreads();
        sm[t] += add;
        __syncthreads();
    }
    if (i < NN) incl[i] = sm[t];
    if (t == SCAN_BS - 1) bsum[blockIdx.x] = sm[t];

    // fused scan2 on the last block to finish
    __shared__ int lastFlag;
    __shared__ int sb[128];
    __threadfence();
    if (t == 0) lastFlag = (atomicAdd(cnt, 1) == (int)gridDim.x - 1) ? 1 : 0;
    __syncthreads();
    if (lastFlag) {
        int v = 0;
        if (t < SCAN_NB) v = atomicAdd(&bsum[t], 0);   // coherent read
        if (t < 128) sb[t] = (t < SCAN_NB) ? v : 0;
        __syncthreads();
        for (int d = 1; d < 128; d <<= 1) {
            const int add = (t < 128 && t >= d) ? sb[t - d] : 0;
            __syncthreads();
            if (t < 128) sb[t] += add;
            __syncthreads();
        }
        if (t < SCAN_NB) bsum[t] = sb[t] - v;   // exclusive prefix
    }
}

__global__ __launch_bounds__(SCAN_BS)
void scan3_kernel(const int* __restrict__ incl, const int* __restrict__ deg,
                  const int* __restrict__ bsum, int* __restrict__ offs)
{
    const int t = threadIdx.x;
    const int i = blockIdx.x * SCAN_BS + t;
    if (i < NN) offs[i] = incl[i] - deg[i] + bsum[blockIdx.x];
    if (i == 0) offs[NN] = NE;
}

// ---------------------------------------------------------------------------
// Conv aggregation (unchanged from R11)
// ---------------------------------------------------------------------------
__global__ __launch_bounds__(256, 8)
void conv_agg_kernel(const int* __restrict__ offs,
                     const int* __restrict__ csr_src,
                     const unsigned* __restrict__ ea2,
                     const float* __restrict__ We,
                     const _Float16* __restrict__ ksb,
                     const _Float16* __restrict__ qvb,
                     _Float16* __restrict__ outh)
{
    const int t    = threadIdx.x;
    const int lane = t & 63;
    const int n    = blockIdx.x * 4 + (t >> 6);
    if (n >= NN) return;

    __half2 w2[21];
#pragma unroll
    for (int q = 0; q < 21; ++q) {
        const float2 wq = *reinterpret_cast<const float2*>(&We[q * HH + 2 * lane]);
        w2[q] = __floats2half2_rn(wq.x, wq.y);
    }

    const uint2 ks = *reinterpret_cast<const uint2*>(ksb + (size_t)n * 256 + lane * 4);
    const __half2 k2 = __builtin_bit_cast(__half2, ks.x);   // k' = -log2e * k
    const __half2 s2 = __builtin_bit_cast(__half2, ks.y);
    const __half2 one2 = __float2half2_rn(1.f);
    const __half2 cm2  = __float2half2_rn(-2.88539008f);    // -2*log2e

    const int j0 = __builtin_amdgcn_readfirstlane(offs[n]);
    const int j1 = __builtin_amdgcn_readfirstlane(offs[n + 1]);
    float acc0 = 0.f, acc1 = 0.f;

#define GATHER(S) (*reinterpret_cast<const uint2*>(qvb + (size_t)(S) * 256 + lane * 4))

#define EDGE(QV, J) { \
    const __half2* aa_ = reinterpret_cast<const __half2*>(ea2 + (size_t)(J) * 21); \
    __half2 e01_ = __float2half2_rn(0.f); \
    _Pragma("unroll") \
    for (int q_ = 0; q_ < 21; ++q_) e01_ = __hfma2(aa_[q_], w2[q_], e01_); \
    const __half2 q2_ = __builtin_bit_cast(__half2, (QV).x); \
    const __half2 v2_ = __builtin_bit_cast(__half2, (QV).y); \
    const __half2 arg_ = __hadd2(k2, __hfma2(cm2, e01_, q2_)); \
    const __half2 gate_ = h2rcp(__hadd2(one2, h2exp2(arg_))); \
    const __half2 m_ = __hmul2(gate_, __hadd2(v2_, e01_)); \
    acc0 += __low2float(m_); \
    acc1 += __high2float(m_); }

    int j = j0;
    for (; j + 4 <= j1; j += 4) {
        const int sa = csr_src[j],     sb = csr_src[j + 1];
        const int sc = csr_src[j + 2], sd = csr_src[j + 3];
        const uint2 qva = GATHER(sa);
        const uint2 qvb_ = GATHER(sb);
        const uint2 qvc = GATHER(sc);
        const uint2 qvd = GATHER(sd);
        EDGE(qva, j)
        EDGE(qvb_, j + 1)
        EDGE(qvc, j + 2)
        EDGE(qvd, j + 3)
    }
    for (; j < j1; ++j) {
        const int s_ = csr_src[j];
        const uint2 qv = GATHER(s_);
        EDGE(qv, j)
    }
#undef GATHER
#undef EDGE

    const float r0 = fmaxf(acc0 + __low2float(s2), 0.f);
    const float r1 = fmaxf(acc1 + __high2float(s2), 0.f);
    const __half2 res = __floats2half2_rn(r0, r1);
    *reinterpret_cast<__half2*>(outh + (size_t)n * HH + 2 * lane) = res;
}

// ---------------------------------------------------------------------------
extern "C" void kernel_launch(void* const* d_in, const int* in_sizes, int n_in,
                              void* d_out, int out_size, void* d_ws, size_t ws_size,
                              hipStream_t stream)
{
    const float* G   = (const float*)d_in[0];
    const int*   ei  = (const int*)  d_in[1];
    const float* ea  = (const float*)d_in[2];
    const float* We1 = (const float*)d_in[3];  const float* be1 = (const float*)d_in[4];
    const float* We2 = (const float*)d_in[5];  const float* be2 = (const float*)d_in[6];
    const float* We3 = (const float*)d_in[7];  const float* be3 = (const float*)d_in[8];
    const float* c1_Wk = (const float*)d_in[9];  const float* c1_bk = (const float*)d_in[10];
    const float* c1_Wq = (const float*)d_in[11]; const float* c1_bq = (const float*)d_in[12];
    const float* c1_Wv = (const float*)d_in[13]; const float* c1_bv = (const float*)d_in[14];
    const float* c1_We = (const float*)d_in[15];
    const float* c1_Ws = (const float*)d_in[16]; const float* c1_bs = (const float*)d_in[17];
    const float* c2_Wk = (const float*)d_in[18]; const float* c2_bk = (const float*)d_in[19];
    const float* c2_Wq = (const float*)d_in[20]; const float* c2_bq = (const float*)d_in[21];
    const float* c2_Wv = (const float*)d_in[22]; const float* c2_bv = (const float*)d_in[23];
    const float* c2_We = (const float*)d_in[24];
    const float* c2_Ws = (const float*)d_in[25]; const float* c2_bs = (const float*)d_in[26];
    const float* Wg1 = (const float*)d_in[27]; const float* bg1 = (const float*)d_in[28];
    const float* Wg2 = (const float*)d_in[29]; const float* bg2 = (const float*)d_in[30];
    const float* Wl1 = (const float*)d_in[31]; const float* bl1 = (const float*)d_in[32];
    const float* Wl2 = (const float*)d_in[33]; const float* bl2 = (const float*)d_in[34];
    const float* Wl3 = (const float*)d_in[35]; const float* bl3 = (const float*)d_in[36];

    float* out = (float*)d_out;

    // ---- workspace layout
    char* ws = (char*)d_ws;
    size_t off = 0;
    _Float16* wps  = (_Float16*)(ws + off); off += 270336 * 2;
    _Float16* hA   = (_Float16*)(ws + off); off += (size_t)NN * 128 * 2;
    _Float16* hB   = (_Float16*)(ws + off); off += (size_t)NN * 128 * 2;
    _Float16* ksb  = (_Float16*)(ws + off); off += (size_t)NN * 256 * 2;
    _Float16* qvb  = (_Float16*)(ws + off); off += (size_t)NN * 256 * 2;
    unsigned* ea2  = (unsigned*)(ws + off); off += (size_t)NE * 21 * 4;
    // zeroed region: deg | cur | gsum | cnts
    int*      deg  = (int*)     (ws + off); off += (size_t)NN * 4;
    int*      cur  = (int*)     (ws + off); off += (size_t)NN * 4;
    float*    gsum = (float*)   (ws + off); off += 256 * 4;
    int*      cnts = (int*)     (ws + off); off += 8 * 4;
    float*    gvec = (float*)   (ws + off); off += 256 * 4;
    int*      incl = (int*)     (ws + off); off += (size_t)NN * 4;
    int*      bsum = (int*)     (ws + off); off += 128 * 4;
    int*      offs = (int*)     (ws + off); off += (size_t)(NN + 2) * 4;
    int*      csr_src = (int*)  (ws + off); off += (size_t)NE * 4;

    const int O_We1 = 0,      O_We2 = 8192,   O_We3 = 24576;
    const int O_c1k = 40960,  O_c1s = 57344,  O_c1q = 73728,  O_c1v = 90112;
    const int O_c2k = 106496, O_c2s = 122880, O_c2q = 139264, O_c2v = 155648;
    const int O_Wg1 = 172032, O_Wg2 = 188416, O_Wl1 = 204800, O_Wl2 = 237568;

    const dim3 blk(256);
    const int  MT = (NN + 63) / 64;       // 782
    const int  AGGB = (NN + 3) / 4;

    // ---- prep (weights transpose + degree histogram) after zeroing counters
    hipMemsetAsync(deg, 0, (size_t)(2 * NN + 256 + 8) * 4, stream);
    prep_kernel<<<dim3(480 + EBLK), blk, 0, stream>>>(
        We1, We2, We3, c1_Wk, c1_Ws, c1_Wq, c1_Wv,
        c2_Wk, c2_Ws, c2_Wq, c2_Wv, Wg1, Wg2, Wl1, Wl2, wps, ei, deg);

    scan1_kernel<<<dim3(SCAN_NB), dim3(SCAN_BS), 0, stream>>>(deg, incl, bsum, cnts);
    scan3_kernel<<<dim3(SCAN_NB), dim3(SCAN_BS), 0, stream>>>(incl, deg, bsum, offs);

    // ---- scatter + ea2 + fused node MLP (overlapped in one dispatch)
    phase5_kernel<<<dim3(EBLK + MT), blk, 0, stream>>>(
        ei, offs, cur, ea, csr_src, ea2, G,
        wps + O_We1, be1, wps + O_We2, be2, wps + O_We3, be3, hA, NN);

    // ---- conv1
    kqvs_kernel<<<dim3(MT), dim3(512), 0, stream>>>(hA,
        wps + O_c1k, wps + O_c1s, wps + O_c1q, wps + O_c1v,
        c1_bk, c1_bs, c1_bq, c1_bv, ksb, qvb, NN);
    conv_agg_kernel<<<dim3(AGGB), blk, 0, stream>>>(offs, csr_src, ea2, c1_We,
        ksb, qvb, hB);

    // ---- conv2
    kqvs_kernel<<<dim3(MT), dim3(512), 0, stream>>>(hB,
        wps + O_c2k, wps + O_c2s, wps + O_c2q, wps + O_c2v,
        c2_bk, c2_bs, c2_bq, c2_bv, ksb, qvb, NN);
    conv_agg_kernel<<<dim3(AGGB), blk, 0, stream>>>(offs, csr_src, ea2, c2_We,
        ksb, qvb, hA);

    // ---- graph MLP (+colsum, last-block gvec) -> hB
    graph2_kernel<<<dim3(MT), blk, 0, stream>>>(hA,
        wps + O_Wg1, bg1, wps + O_Wg2, bg2, hB, gsum,
        Wl1, bl1, gvec, cnts + 1, 1.f / NN, NN);

    // ---- head -> out
    head3_kernel<<<dim3(MT), blk, 0, stream>>>(hB,
        wps + O_Wl1, gvec, wps + O_Wl2, bl2, Wl3, bl3, out, NN);
}

// Round 13
// 505.433 us; speedup vs baseline: 1.1484x; 1.1484x over previous
//
#include <hip/hip_runtime.h>
#include <hip/hip_fp16.h>

#define NN 50000
#define NE 800000
#define HH 128
#define SCAN_BS 512
#define SCAN_NB 98
#define LDK 40
#define LDA 136
#define LDU 264
#define EBLK ((NE + 255) / 256)   // 3125

typedef _Float16 half8 __attribute__((ext_vector_type(8)));
typedef float f32x4  __attribute__((ext_vector_type(4)));

// ---------------------------------------------------------------------------
// prep: blocks [0,480) transpose+cast weights; blocks [480, 480+EBLK) histogram.
// ---------------------------------------------------------------------------
__global__ __launch_bounds__(256)
void prep_kernel(const float* __restrict__ s0,  const float* __restrict__ s1,
                 const float* __restrict__ s2,  const float* __restrict__ s3,
                 const float* __restrict__ s4,  const float* __restrict__ s5,
                 const float* __restrict__ s6,  const float* __restrict__ s7,
                 const float* __restrict__ s8,  const float* __restrict__ s9,
                 const float* __restrict__ s10, const float* __restrict__ s11,
                 const float* __restrict__ s12, const float* __restrict__ s13,
                 const float* __restrict__ s14, _Float16* __restrict__ wps,
                 const int* __restrict__ ei, int* __restrict__ deg)
{
    const int b = blockIdx.x;
    if (b >= 480) {
        const int e = (b - 480) * 256 + threadIdx.x;
        if (e < NE) atomicAdd(&deg[ei[NE + e]], 1);
        return;
    }
    const float* srcs[15] = {s0,s1,s2,s3,s4,s5,s6,s7,s8,s9,s10,s11,s12,s13,s14};
    const int Ks[15]   = {64,128,128,128,128,128,128,128,128,128,128,128,128,128,256};
    const int logKs[15]= { 6,  7,  7,  7,  7,  7,  7,  7,  7,  7,  7,  7,  7,  7,  8};
    const int off[15]  = {0,8192,24576,40960,57344,73728,90112,106496,122880,
                          139264,155648,172032,188416,204800,237568};

    const int mi = b >> 5;
    const int bx = b & 31;
    const float* src = srcs[mi];
    const int K = Ks[mi], logK = logKs[mi];
    const int N = (mi == 13) ? 256 : 128;
    _Float16* dst = wps + off[mi];
    const int tot = K * N;
    const int base = (bx * 256 + threadIdx.x) * 4;
    if (base >= tot) return;
    const int n = base >> logK;
    const int k = base & (K - 1);
#pragma unroll
    for (int x = 0; x < 4; ++x)
        dst[(size_t)n * K + k + x] = (_Float16)src[(size_t)(k + x) * N + n];
}

// ---------------------------------------------------------------------------
// LDS->LDS layer (256-thread kernels)
// ---------------------------------------------------------------------------
template<bool RELU>
__device__ __forceinline__ void layer_l2l(
    const _Float16* __restrict__ actA, int lda, int K,
    const _Float16* __restrict__ Bt,
    const float* __restrict__ bias,
    _Float16* __restrict__ actO, int ldo, int oc0,
    _Float16* __restrict__ Bs)
{
    const int t = threadIdx.x, lane = t & 63;
    const int wr = (t >> 6) >> 1, wc = (t >> 6) & 1;
    const int fr = lane & 15, fg = lane >> 4;
    const int rb = t >> 1, kb = (t & 1) * 16;

    f32x4 acc[2][4] = {};
    for (int k0 = 0; k0 < K; k0 += 32) {
        const _Float16* p = Bt + (size_t)rb * K + k0 + kb;
        const half8 v0 = *reinterpret_cast<const half8*>(p);
        const half8 v1 = *reinterpret_cast<const half8*>(p + 8);
        *reinterpret_cast<half8*>(&Bs[rb * LDK + kb])     = v0;
        *reinterpret_cast<half8*>(&Bs[rb * LDK + kb + 8]) = v1;
        __syncthreads();

        half8 a[2], bfr[4];
#pragma unroll
        for (int i = 0; i < 2; ++i)
            a[i] = *reinterpret_cast<const half8*>(&actA[(wr * 32 + i * 16 + fr) * lda + k0 + fg * 8]);
#pragma unroll
        for (int j = 0; j < 4; ++j)
            bfr[j] = *reinterpret_cast<const half8*>(&Bs[(wc * 64 + j * 16 + fr) * LDK + fg * 8]);
#pragma unroll
        for (int i = 0; i < 2; ++i)
#pragma unroll
            for (int j = 0; j < 4; ++j)
                acc[i][j] = __builtin_amdgcn_mfma_f32_16x16x32_f16(a[i], bfr[j], acc[i][j], 0, 0, 0);
        __syncthreads();
    }
#pragma unroll
    for (int j = 0; j < 4; ++j) {
        const int gnl = wc * 64 + j * 16 + fr;
        const float bv = bias[gnl];
#pragma unroll
        for (int i = 0; i < 2; ++i)
#pragma unroll
            for (int rr = 0; rr < 4; ++rr) {
                float v = acc[i][j][rr] + bv;
                if (RELU) v = fmaxf(v, 0.f);
                actO[(wr * 32 + i * 16 + fg * 4 + rr) * ldo + oc0 + gnl] = (_Float16)v;
            }
    }
    __syncthreads();
}

// ---------------------------------------------------------------------------
// phase5: blocks [0,EBLK) scatter + CSR-ordered ea2; rest run fused node MLP.
// ---------------------------------------------------------------------------
__global__ __launch_bounds__(256)
void phase5_kernel(const int* __restrict__ ei, const int* __restrict__ offs,
                   int* __restrict__ cur, const float* __restrict__ ea,
                   int* __restrict__ csr_src, unsigned* __restrict__ ea2,
                   const float* __restrict__ G,
                   const _Float16* __restrict__ W1, const float* __restrict__ b1,
                   const _Float16* __restrict__ W2, const float* __restrict__ b2,
                   const _Float16* __restrict__ W3, const float* __restrict__ b3,
                   _Float16* __restrict__ outf, int M)
{
    __shared__ __attribute__((aligned(16))) _Float16 AA[64 * LDA];
    __shared__ __attribute__((aligned(16))) _Float16 AB[64 * LDA];
    __shared__ __attribute__((aligned(16))) _Float16 Bs[128 * LDK];

    const int t = threadIdx.x;
    if (blockIdx.x < EBLK) {
        const int e = blockIdx.x * 256 + t;
        if (e >= NE) return;
        const int d = ei[NE + e];
        const int p = offs[d] + atomicAdd(&cur[d], 1);
        csr_src[p] = ei[e];
        const float* src = ea + (size_t)e * 21;
        unsigned* dst = ea2 + (size_t)p * 21;
#pragma unroll
        for (int q = 0; q < 21; ++q) {
            const __half2 h = __floats2half2_rn(src[q], src[q]);
            dst[q] = __builtin_bit_cast(unsigned, h);
        }
        return;
    }

    const int m0 = (blockIdx.x - EBLK) << 6;
    {
        const int r  = t >> 2;
        const int c0 = (t & 3) * 16;
        const int gm = m0 + r;
#pragma unroll
        for (int h = 0; h < 2; ++h) {
            float4 v0 = make_float4(0.f, 0.f, 0.f, 0.f), v1 = v0;
            if (gm < M) {
                v0 = *reinterpret_cast<const float4*>(G + (size_t)gm * 64 + c0 + h * 8);
                v1 = *reinterpret_cast<const float4*>(G + (size_t)gm * 64 + c0 + h * 8 + 4);
            }
            half8 hv;
            hv[0] = (_Float16)v0.x; hv[1] = (_Float16)v0.y;
            hv[2] = (_Float16)v0.z; hv[3] = (_Float16)v0.w;
            hv[4] = (_Float16)v1.x; hv[5] = (_Float16)v1.y;
            hv[6] = (_Float16)v1.z; hv[7] = (_Float16)v1.w;
            *reinterpret_cast<half8*>(&AA[r * LDA + c0 + h * 8]) = hv;
        }
    }
    __syncthreads();

    layer_l2l<true>(AA, LDA, 64,  W1, b1, AB, LDA, 0, Bs);
    layer_l2l<true>(AB, LDA, 128, W2, b2, AA, LDA, 0, Bs);
    layer_l2l<true>(AA, LDA, 128, W3, b3, AB, LDA, 0, Bs);

    {
        const int r  = t >> 2;
        const int c0 = (t & 3) * 32;
        const int gm = m0 + r;
        if (gm < M) {
#pragma unroll
            for (int x = 0; x < 32; x += 8)
                *reinterpret_cast<half8*>(outf + (size_t)gm * 128 + c0 + x) =
                    *reinterpret_cast<const half8*>(&AB[r * LDA + c0 + x]);
        }
    }
}

// ---------------------------------------------------------------------------
// kqvs v2: one 64x512 GEMM per block. 512 threads = 8 waves; wave (wr, wc)
// covers 32 rows x 128 cols; wc selects the weight set {k', s, q', v}.
// ---------------------------------------------------------------------------
__global__ __launch_bounds__(512)
void kqvs_kernel(const _Float16* __restrict__ act,
                 const _Float16* __restrict__ B0, const _Float16* __restrict__ B1,
                 const _Float16* __restrict__ B2, const _Float16* __restrict__ B3,
                 const float* __restrict__ b0, const float* __restrict__ b1,
                 const float* __restrict__ b2, const float* __restrict__ b3,
                 _Float16* __restrict__ ksb, _Float16* __restrict__ qvb, int M)
{
    __shared__ __attribute__((aligned(16))) _Float16 AA[64 * LDA];    // 17.4 KB
    __shared__ __attribute__((aligned(16))) _Float16 Bs[512 * LDK];   // 41 KB

    const int t    = threadIdx.x, lane = t & 63;
    const int wid  = t >> 6;                  // 0..7
    const int wr   = wid >> 2;                // rows half
    const int wc   = wid & 3;                 // weight set
    const int fr   = lane & 15, fg = lane >> 4;
    const int m0   = blockIdx.x << 6;

    // stage activations 64x128
    {
        const int r  = t >> 3;
        const int c0 = (t & 7) * 16;
        const int gm = m0 + r;
        half8 v0 = {0,0,0,0,0,0,0,0}, v1 = v0;
        if (gm < M) {
            v0 = *reinterpret_cast<const half8*>(act + (size_t)gm * 128 + c0);
            v1 = *reinterpret_cast<const half8*>(act + (size_t)gm * 128 + c0 + 8);
        }
        *reinterpret_cast<half8*>(&AA[r * LDA + c0])     = v0;
        *reinterpret_cast<half8*>(&AA[r * LDA + c0 + 8]) = v1;
    }

    const _Float16* Bt_stage = (t < 128) ? B0 : (t < 256) ? B1 : (t < 384) ? B2 : B3;
    const _Float16* srow = Bt_stage + (size_t)(t & 127) * 128;

    __syncthreads();

    f32x4 acc[2][8] = {};
    for (int k0 = 0; k0 < 128; k0 += 32) {
        {
            const half8 v0 = *reinterpret_cast<const half8*>(srow + k0);
            const half8 v1 = *reinterpret_cast<const half8*>(srow + k0 + 8);
            const half8 v2 = *reinterpret_cast<const half8*>(srow + k0 + 16);
            const half8 v3 = *reinterpret_cast<const half8*>(srow + k0 + 24);
            *reinterpret_cast<half8*>(&Bs[t * LDK + 0])  = v0;
            *reinterpret_cast<half8*>(&Bs[t * LDK + 8])  = v1;
            *reinterpret_cast<half8*>(&Bs[t * LDK + 16]) = v2;
            *reinterpret_cast<half8*>(&Bs[t * LDK + 24]) = v3;
        }
        __syncthreads();

        half8 a[2], b[8];
#pragma unroll
        for (int i = 0; i < 2; ++i)
            a[i] = *reinterpret_cast<const half8*>(&AA[(wr * 32 + i * 16 + fr) * LDA + k0 + fg * 8]);
#pragma unroll
        for (int j = 0; j < 8; ++j)
            b[j] = *reinterpret_cast<const half8*>(&Bs[(wc * 128 + j * 16 + fr) * LDK + fg * 8]);
#pragma unroll
        for (int i = 0; i < 2; ++i)
#pragma unroll
            for (int j = 0; j < 8; ++j)
                acc[i][j] = __builtin_amdgcn_mfma_f32_16x16x32_f16(a[i], b[j], acc[i][j], 0, 0, 0);
        __syncthreads();
    }

    _Float16* dst  = (wc < 2) ? ksb : qvb;
    const int  sub = (wc & 1) * 2;
    const float scl = (wc == 0 || wc == 2) ? -1.44269504f : 1.0f;   // k', q'
    const float* bt = (wc == 0) ? b0 : (wc == 1) ? b1 : (wc == 2) ? b2 : b3;
#pragma unroll
    for (int j = 0; j < 8; ++j) {
        const int gnl = j * 16 + fr;
        const int pos = ((gnl >> 1) << 2) + sub + (gnl & 1);
        const float bv = bt[gnl];
#pragma unroll
        for (int i = 0; i < 2; ++i) {
            const int mbase = m0 + wr * 32 + i * 16 + fg * 4;
#pragma unroll
            for (int rr = 0; rr < 4; ++rr) {
                const int gm = mbase + rr;
                if (gm < M)
                    dst[(size_t)gm * 256 + pos] = (_Float16)((acc[i][j][rr] + bv) * scl);
            }
        }
    }
}

// ---------------------------------------------------------------------------
// Fused graph MLP (+colsum) — no last-block fusion (threadfence regression R12)
// ---------------------------------------------------------------------------
__global__ __launch_bounds__(256)
void graph2_kernel(const _Float16* __restrict__ act,
                   const _Float16* __restrict__ Wg1t, const float* __restrict__ bg1,
                   const _Float16* __restrict__ Wg2t, const float* __restrict__ bg2,
                   _Float16* __restrict__ g2f, float* __restrict__ gsum, int M)
{
    __shared__ __attribute__((aligned(16))) _Float16 AA[64 * LDA];
    __shared__ __attribute__((aligned(16))) _Float16 AB[64 * LDA];
    __shared__ __attribute__((aligned(16))) _Float16 Bs[128 * LDK];

    const int t  = threadIdx.x, lane = t & 63;
    const int m0 = blockIdx.x << 6;
    const int wr = (t >> 6) >> 1, wc = (t >> 6) & 1;
    const int fr = lane & 15, fg = lane >> 4;
    const int rb = t >> 1, kb = (t & 1) * 16;

    {
        const int r  = t >> 2;
        const int c0 = (t & 3) * 32;
        const int gm = m0 + r;
#pragma unroll
        for (int x = 0; x < 32; x += 8) {
            half8 v = {0,0,0,0,0,0,0,0};
            if (gm < M) v = *reinterpret_cast<const half8*>(act + (size_t)gm * 128 + c0 + x);
            *reinterpret_cast<half8*>(&AA[r * LDA + c0 + x]) = v;
        }
    }
    __syncthreads();

    layer_l2l<true>(AA, LDA, 128, Wg1t, bg1, AB, LDA, 0, Bs);

    f32x4 acc[2][4] = {};
    for (int k0 = 0; k0 < 128; k0 += 32) {
        const _Float16* p = Wg2t + (size_t)rb * 128 + k0 + kb;
        const half8 v0 = *reinterpret_cast<const half8*>(p);
        const half8 v1 = *reinterpret_cast<const half8*>(p + 8);
        *reinterpret_cast<half8*>(&Bs[rb * LDK + kb])     = v0;
        *reinterpret_cast<half8*>(&Bs[rb * LDK + kb + 8]) = v1;
        __syncthreads();
        half8 a[2], b[4];
#pragma unroll
        for (int i = 0; i < 2; ++i)
            a[i] = *reinterpret_cast<const half8*>(&AB[(wr * 32 + i * 16 + fr) * LDA + k0 + fg * 8]);
#pragma unroll
        for (int j = 0; j < 4; ++j)
            b[j] = *reinterpret_cast<const half8*>(&Bs[(wc * 64 + j * 16 + fr) * LDK + fg * 8]);
#pragma unroll
        for (int i = 0; i < 2; ++i)
#pragma unroll
            for (int j = 0; j < 4; ++j)
                acc[i][j] = __builtin_amdgcn_mfma_f32_16x16x32_f16(a[i], b[j], acc[i][j], 0, 0, 0);
        __syncthreads();
    }
#pragma unroll
    for (int j = 0; j < 4; ++j) {
        const int gn = wc * 64 + j * 16 + fr;
        const float bv = bg2[gn];
        float csum = 0.f;
#pragma unroll
        for (int i = 0; i < 2; ++i) {
            const int mbase = m0 + wr * 32 + i * 16 + fg * 4;
#pragma unroll
            for (int rr = 0; rr < 4; ++rr) {
                const int gm = mbase + rr;
                if (gm < M) {
                    const float v = acc[i][j][rr] + bv;
                    csum += v;
                    g2f[(size_t)gm * 128 + gn] = (_Float16)v;
                }
            }
        }
        csum += __shfl_xor(csum, 16);
        csum += __shfl_xor(csum, 32);
        if (fg == 0) atomicAdd(&gsum[gn], csum);
    }
}

// ---------------------------------------------------------------------------
// Fused head (unchanged)
// ---------------------------------------------------------------------------
__global__ __launch_bounds__(256)
void head3_kernel(const _Float16* __restrict__ g2f,
                  const _Float16* __restrict__ Wl1t,
                  const float* __restrict__ gvec,
                  const _Float16* __restrict__ Wl2t,
                  const float* __restrict__ bl2,
                  const float* __restrict__ wl3,
                  const float* __restrict__ bl3,
                  float* __restrict__ out, int M)
{
    __shared__ __attribute__((aligned(16))) _Float16 AA[64 * LDA];
    __shared__ __attribute__((aligned(16))) _Float16 UB[64 * LDU];
    __shared__ __attribute__((aligned(16))) _Float16 Bs[128 * LDK];
    __shared__ float psum[2][64];

    const int t  = threadIdx.x, lane = t & 63;
    const int m0 = blockIdx.x << 6;
    const int wr = (t >> 6) >> 1, wc = (t >> 6) & 1;
    const int fr = lane & 15, fg = lane >> 4;
    const int rb = t >> 1, kb = (t & 1) * 16;

    {
        const int r  = t >> 2;
        const int c0 = (t & 3) * 32;
        const int gm = m0 + r;
#pragma unroll
        for (int x = 0; x < 32; x += 8) {
            half8 v = {0,0,0,0,0,0,0,0};
            if (gm < M) v = *reinterpret_cast<const half8*>(g2f + (size_t)gm * 128 + c0 + x);
            *reinterpret_cast<half8*>(&AA[r * LDA + c0 + x]) = v;
        }
    }
    __syncthreads();

    layer_l2l<true>(AA, LDA, 128, Wl1t,             gvec,       UB, LDU, 0,   Bs);
    layer_l2l<true>(AA, LDA, 128, Wl1t + 128 * 128, gvec + 128, UB, LDU, 128, Bs);

    f32x4 acc[2][4] = {};
    for (int k0 = 0; k0 < 256; k0 += 32) {
        const _Float16* p = Wl2t + (size_t)rb * 256 + k0 + kb;
        const half8 v0 = *reinterpret_cast<const half8*>(p);
        const half8 v1 = *reinterpret_cast<const half8*>(p + 8);
        *reinterpret_cast<half8*>(&Bs[rb * LDK + kb])     = v0;
        *reinterpret_cast<half8*>(&Bs[rb * LDK + kb + 8]) = v1;
        __syncthreads();
        half8 a[2], b[4];
#pragma unroll
        for (int i = 0; i < 2; ++i)
            a[i] = *reinterpret_cast<const half8*>(&UB[(wr * 32 + i * 16 + fr) * LDU + k0 + fg * 8]);
#pragma unroll
        for (int j = 0; j < 4; ++j)
            b[j] = *reinterpret_cast<const half8*>(&Bs[(wc * 64 + j * 16 + fr) * LDK + fg * 8]);
#pragma unroll
        for (int i = 0; i < 2; ++i)
#pragma unroll
            for (int j = 0; j < 4; ++j)
                acc[i][j] = __builtin_amdgcn_mfma_f32_16x16x32_f16(a[i], b[j], acc[i][j], 0, 0, 0);
        __syncthreads();
    }

    float p[2][4] = {};
#pragma unroll
    for (int j = 0; j < 4; ++j) {
        const int gnl = wc * 64 + j * 16 + fr;
        const float bv = bl2[gnl];
        const float wv = wl3[gnl];
#pragma unroll
        for (int i = 0; i < 2; ++i)
#pragma unroll
            for (int rr = 0; rr < 4; ++rr)
                p[i][rr] += fmaxf(acc[i][j][rr] + bv, 0.f) * wv;
    }
#pragma unroll
    for (int i = 0; i < 2; ++i)
#pragma unroll
        for (int rr = 0; rr < 4; ++rr) {
            float s = p[i][rr];
            s += __shfl_xor(s, 1);
            s += __shfl_xor(s, 2);
            s += __shfl_xor(s, 4);
            s += __shfl_xor(s, 8);
            p[i][rr] = s;
        }
    if (fr == 0) {
#pragma unroll
        for (int i = 0; i < 2; ++i)
#pragma unroll
            for (int rr = 0; rr < 4; ++rr)
                psum[wc][wr * 32 + i * 16 + fg * 4 + rr] = p[i][rr];
    }
    __syncthreads();
    if (t < 64) {
        const int gm = m0 + t;
        if (gm < M) out[gm] = psum[0][t] + psum[1][t] + bl3[0];
    }
}

// ---------------------------------------------------------------------------
// scans (separate kernels — last-block fusion reverted)
// ---------------------------------------------------------------------------
__global__ __launch_bounds__(SCAN_BS)
void scan1_kernel(const int* __restrict__ deg, int* __restrict__ incl,
                  int* __restrict__ bsum)
{
    __shared__ int sm[SCAN_BS];
    const int t = threadIdx.x;
    const int i = blockIdx.x * SCAN_BS + t;
    sm[t] = (i < NN) ? deg[i] : 0;
    __syncthreads();
    for (int d = 1; d < SCAN_BS; d <<= 1) {
        const int add = (t >= d) ? sm[t - d] : 0;
        __syncthreads();
        sm[t] += add;
        __syncthreads();
    }
    if (i < NN) incl[i] = sm[t];
    if (t == SCAN_BS - 1) bsum[blockIdx.x] = sm[t];
}

__global__ __launch_bounds__(128)
void scan2_kernel(int* __restrict__ bsum)
{
    __shared__ int sm[128];
    const int t = threadIdx.x;
    const int v = (t < SCAN_NB) ? bsum[t] : 0;
    sm[t] = v;
    __syncthreads();
    for (int d = 1; d < 128; d <<= 1) {
        const int add = (t >= d) ? sm[t - d] : 0;
        __syncthreads();
        sm[t] += add;
        __syncthreads();
    }
    if (t < SCAN_NB) bsum[t] = sm[t] - v;
}

__global__ __launch_bounds__(SCAN_BS)
void scan3_kernel(const int* __restrict__ incl, const int* __restrict__ deg,
                  const int* __restrict__ bsum, int* __restrict__ offs)
{
    const int t = threadIdx.x;
    const int i = blockIdx.x * SCAN_BS + t;
    if (i < NN) offs[i] = incl[i] - deg[i] + bsum[blockIdx.x];
    if (i == 0) offs[NN] = NE;
}

// ---------------------------------------------------------------------------
// Conv aggregation (unchanged)
// ---------------------------------------------------------------------------
__global__ __launch_bounds__(256, 8)
void conv_agg_kernel(const int* __restrict__ offs,
                     const int* __restrict__ csr_src,
                     const unsigned* __restrict__ ea2,
                     const float* __restrict__ We,
                     const _Float16* __restrict__ ksb,
                     const _Float16* __restrict__ qvb,
                     _Float16* __restrict__ outh)
{
    const int t    = threadIdx.x;
    const int lane = t & 63;
    const int n    = blockIdx.x * 4 + (t >> 6);
    if (n >= NN) return;

    __half2 w2[21];
#pragma unroll
    for (int q = 0; q < 21; ++q) {
        const float2 wq = *reinterpret_cast<const float2*>(&We[q * HH + 2 * lane]);
        w2[q] = __floats2half2_rn(wq.x, wq.y);
    }

    const uint2 ks = *reinterpret_cast<const uint2*>(ksb + (size_t)n * 256 + lane * 4);
    const __half2 k2 = __builtin_bit_cast(__half2, ks.x);   // k' = -log2e * k
    const __half2 s2 = __builtin_bit_cast(__half2, ks.y);
    const __half2 one2 = __float2half2_rn(1.f);
    const __half2 cm2  = __float2half2_rn(-2.88539008f);    // -2*log2e

    const int j0 = __builtin_amdgcn_readfirstlane(offs[n]);
    const int j1 = __builtin_amdgcn_readfirstlane(offs[n + 1]);
    float acc0 = 0.f, acc1 = 0.f;

#define GATHER(S) (*reinterpret_cast<const uint2*>(qvb + (size_t)(S) * 256 + lane * 4))

#define EDGE(QV, J) { \
    const __half2* aa_ = reinterpret_cast<const __half2*>(ea2 + (size_t)(J) * 21); \
    __half2 e01_ = __float2half2_rn(0.f); \
    _Pragma("unroll") \
    for (int q_ = 0; q_ < 21; ++q_) e01_ = __hfma2(aa_[q_], w2[q_], e01_); \
    const __half2 q2_ = __builtin_bit_cast(__half2, (QV).x); \
    const __half2 v2_ = __builtin_bit_cast(__half2, (QV).y); \
    const __half2 arg_ = __hadd2(k2, __hfma2(cm2, e01_, q2_)); \
    const __half2 gate_ = h2rcp(__hadd2(one2, h2exp2(arg_))); \
    const __half2 m_ = __hmul2(gate_, __hadd2(v2_, e01_)); \
    acc0 += __low2float(m_); \
    acc1 += __high2float(m_); }

    int j = j0;
    for (; j + 4 <= j1; j += 4) {
        const int sa = csr_src[j],     sb = csr_src[j + 1];
        const int sc = csr_src[j + 2], sd = csr_src[j + 3];
        const uint2 qva = GATHER(sa);
        const uint2 qvb_ = GATHER(sb);
        const uint2 qvc = GATHER(sc);
        const uint2 qvd = GATHER(sd);
        EDGE(qva, j)
        EDGE(qvb_, j + 1)
        EDGE(qvc, j + 2)
        EDGE(qvd, j + 3)
    }
    for (; j < j1; ++j) {
        const int s_ = csr_src[j];
        const uint2 qv = GATHER(s_);
        EDGE(qv, j)
    }
#undef GATHER
#undef EDGE

    const float r0 = fmaxf(acc0 + __low2float(s2), 0.f);
    const float r1 = fmaxf(acc1 + __high2float(s2), 0.f);
    const __half2 res = __floats2half2_rn(r0, r1);
    *reinterpret_cast<__half2*>(outh + (size_t)n * HH + 2 * lane) = res;
}

// ---------------------------------------------------------------------------
__global__ __launch_bounds__(256)
void gvec_kernel(const float* __restrict__ gsum,
                 const float* __restrict__ Wl1,
                 const float* __restrict__ bl1,
                 float* __restrict__ gvec, float invM)
{
    const int j = threadIdx.x;
    float acc = bl1[j];
    for (int k = 0; k < 128; ++k)
        acc += (gsum[k] * invM) * Wl1[(size_t)(128 + k) * 256 + j];
    gvec[j] = acc;
}

// ---------------------------------------------------------------------------
extern "C" void kernel_launch(void* const* d_in, const int* in_sizes, int n_in,
                              void* d_out, int out_size, void* d_ws, size_t ws_size,
                              hipStream_t stream)
{
    const float* G   = (const float*)d_in[0];
    const int*   ei  = (const int*)  d_in[1];
    const float* ea  = (const float*)d_in[2];
    const float* We1 = (const float*)d_in[3];  const float* be1 = (const float*)d_in[4];
    const float* We2 = (const float*)d_in[5];  const float* be2 = (const float*)d_in[6];
    const float* We3 = (const float*)d_in[7];  const float* be3 = (const float*)d_in[8];
    const float* c1_Wk = (const float*)d_in[9];  const float* c1_bk = (const float*)d_in[10];
    const float* c1_Wq = (const float*)d_in[11]; const float* c1_bq = (const float*)d_in[12];
    const float* c1_Wv = (const float*)d_in[13]; const float* c1_bv = (const float*)d_in[14];
    const float* c1_We = (const float*)d_in[15];
    const float* c1_Ws = (const float*)d_in[16]; const float* c1_bs = (const float*)d_in[17];
    const float* c2_Wk = (const float*)d_in[18]; const float* c2_bk = (const float*)d_in[19];
    const float* c2_Wq = (const float*)d_in[20]; const float* c2_bq = (const float*)d_in[21];
    const float* c2_Wv = (const float*)d_in[22]; const float* c2_bv = (const float*)d_in[23];
    const float* c2_We = (const float*)d_in[24];
    const float* c2_Ws = (const float*)d_in[25]; const float* c2_bs = (const float*)d_in[26];
    const float* Wg1 = (const float*)d_in[27]; const float* bg1 = (const float*)d_in[28];
    const float* Wg2 = (const float*)d_in[29]; const float* bg2 = (const float*)d_in[30];
    const float* Wl1 = (const float*)d_in[31]; const float* bl1 = (const float*)d_in[32];
    const float* Wl2 = (const float*)d_in[33]; const float* bl2 = (const float*)d_in[34];
    const float* Wl3 = (const float*)d_in[35]; const float* bl3 = (const float*)d_in[36];

    float* out = (float*)d_out;

    // ---- workspace layout
    char* ws = (char*)d_ws;
    size_t off = 0;
    _Float16* wps  = (_Float16*)(ws + off); off += 270336 * 2;
    _Float16* hA   = (_Float16*)(ws + off); off += (size_t)NN * 128 * 2;
    _Float16* hB   = (_Float16*)(ws + off); off += (size_t)NN * 128 * 2;
    _Float16* ksb  = (_Float16*)(ws + off); off += (size_t)NN * 256 * 2;
    _Float16* qvb  = (_Float16*)(ws + off); off += (size_t)NN * 256 * 2;
    unsigned* ea2  = (unsigned*)(ws + off); off += (size_t)NE * 21 * 4;
    int*      deg  = (int*)     (ws + off); off += (size_t)NN * 4;
    int*      cur  = (int*)     (ws + off); off += (size_t)NN * 4;
    float*    gsum = (float*)   (ws + off); off += 256 * 4;
    float*    gvec = (float*)   (ws + off); off += 256 * 4;
    int*      incl = (int*)     (ws + off); off += (size_t)NN * 4;
    int*      bsum = (int*)     (ws + off); off += 128 * 4;
    int*      offs = (int*)     (ws + off); off += (size_t)(NN + 2) * 4;
    int*      csr_src = (int*)  (ws + off); off += (size_t)NE * 4;

    const int O_We1 = 0,      O_We2 = 8192,   O_We3 = 24576;
    const int O_c1k = 40960,  O_c1s = 57344,  O_c1q = 73728,  O_c1v = 90112;
    const int O_c2k = 106496, O_c2s = 122880, O_c2q = 139264, O_c2v = 155648;
    const int O_Wg1 = 172032, O_Wg2 = 188416, O_Wl1 = 204800, O_Wl2 = 237568;

    const dim3 blk(256);
    const int  MT = (NN + 63) / 64;       // 782
    const int  AGGB = (NN + 3) / 4;

    // ---- prep (weights transpose + degree histogram) after zeroing counters
    hipMemsetAsync(deg, 0, (size_t)(2 * NN + 256) * 4, stream);
    prep_kernel<<<dim3(480 + EBLK), blk, 0, stream>>>(
        We1, We2, We3, c1_Wk, c1_Ws, c1_Wq, c1_Wv,
        c2_Wk, c2_Ws, c2_Wq, c2_Wv, Wg1, Wg2, Wl1, Wl2, wps, ei, deg);

    scan1_kernel<<<dim3(SCAN_NB), dim3(SCAN_BS), 0, stream>>>(deg, incl, bsum);
    scan2_kernel<<<dim3(1), dim3(128), 0, stream>>>(bsum);
    scan3_kernel<<<dim3(SCAN_NB), dim3(SCAN_BS), 0, stream>>>(incl, deg, bsum, offs);

    // ---- scatter + ea2 + fused node MLP (overlapped in one dispatch)
    phase5_kernel<<<dim3(EBLK + MT), blk, 0, stream>>>(
        ei, offs, cur, ea, csr_src, ea2, G,
        wps + O_We1, be1, wps + O_We2, be2, wps + O_We3, be3, hA, NN);

    // ---- conv1
    kqvs_kernel<<<dim3(MT), dim3(512), 0, stream>>>(hA,
        wps + O_c1k, wps + O_c1s, wps + O_c1q, wps + O_c1v,
        c1_bk, c1_bs, c1_bq, c1_bv, ksb, qvb, NN);
    conv_agg_kernel<<<dim3(AGGB), blk, 0, stream>>>(offs, csr_src, ea2, c1_We,
        ksb, qvb, hB);

    // ---- conv2
    kqvs_kernel<<<dim3(MT), dim3(512), 0, stream>>>(hB,
        wps + O_c2k, wps + O_c2s, wps + O_c2q, wps + O_c2v,
        c2_bk, c2_bs, c2_bq, c2_bv, ksb, qvb, NN);
    conv_agg_kernel<<<dim3(AGGB), blk, 0, stream>>>(offs, csr_src, ea2, c2_We,
        ksb, qvb, hA);

    // ---- graph MLP (+colsum) -> hB
    graph2_kernel<<<dim3(MT), blk, 0, stream>>>(hA,
        wps + O_Wg1, bg1, wps + O_Wg2, bg2, hB, gsum, NN);

    // ---- graph mean -> gvec
    gvec_kernel<<<dim3(1), dim3(256), 0, stream>>>(gsum, Wl1, bl1, gvec, 1.f / NN);

    // ---- head -> out
    head3_kernel<<<dim3(MT), blk, 0, stream>>>(hB,
        wps + O_Wl1, gvec, wps + O_Wl2, bl2, Wl3, bl3, out, NN);
}

// Round 14
// 459.864 us; speedup vs baseline: 1.2622x; 1.0991x over previous
//
#include <hip/hip_runtime.h>
#include <hip/hip_fp16.h>

#define NN 50000
#define NE 800000
#define HH 128
#define SCAN_BS 512
#define SCAN_NB 98
#define LDK 40
#define LDA 136
#define LDU 264
#define EBLK ((NE + 255) / 256)   // 3125

typedef _Float16 half8 __attribute__((ext_vector_type(8)));
typedef float f32x4  __attribute__((ext_vector_type(4)));

// ---------------------------------------------------------------------------
// prep: blocks [0,480) transpose+cast weights; blocks [480, 480+EBLK) histogram.
// ---------------------------------------------------------------------------
__global__ __launch_bounds__(256)
void prep_kernel(const float* __restrict__ s0,  const float* __restrict__ s1,
                 const float* __restrict__ s2,  const float* __restrict__ s3,
                 const float* __restrict__ s4,  const float* __restrict__ s5,
                 const float* __restrict__ s6,  const float* __restrict__ s7,
                 const float* __restrict__ s8,  const float* __restrict__ s9,
                 const float* __restrict__ s10, const float* __restrict__ s11,
                 const float* __restrict__ s12, const float* __restrict__ s13,
                 const float* __restrict__ s14, _Float16* __restrict__ wps,
                 const int* __restrict__ ei, int* __restrict__ deg)
{
    const int b = blockIdx.x;
    if (b >= 480) {
        const int e = (b - 480) * 256 + threadIdx.x;
        if (e < NE) atomicAdd(&deg[ei[NE + e]], 1);
        return;
    }
    const float* srcs[15] = {s0,s1,s2,s3,s4,s5,s6,s7,s8,s9,s10,s11,s12,s13,s14};
    const int Ks[15]   = {64,128,128,128,128,128,128,128,128,128,128,128,128,128,256};
    const int logKs[15]= { 6,  7,  7,  7,  7,  7,  7,  7,  7,  7,  7,  7,  7,  7,  8};
    const int off[15]  = {0,8192,24576,40960,57344,73728,90112,106496,122880,
                          139264,155648,172032,188416,204800,237568};

    const int mi = b >> 5;
    const int bx = b & 31;
    const float* src = srcs[mi];
    const int K = Ks[mi], logK = logKs[mi];
    const int N = (mi == 13) ? 256 : 128;
    _Float16* dst = wps + off[mi];
    const int tot = K * N;
    const int base = (bx * 256 + threadIdx.x) * 4;
    if (base >= tot) return;
    const int n = base >> logK;
    const int k = base & (K - 1);
#pragma unroll
    for (int x = 0; x < 4; ++x)
        dst[(size_t)n * K + k + x] = (_Float16)src[(size_t)(k + x) * N + n];
}

// ---------------------------------------------------------------------------
// LDS->LDS layer
// ---------------------------------------------------------------------------
template<bool RELU>
__device__ __forceinline__ void layer_l2l(
    const _Float16* __restrict__ actA, int lda, int K,
    const _Float16* __restrict__ Bt,
    const float* __restrict__ bias,
    _Float16* __restrict__ actO, int ldo, int oc0,
    _Float16* __restrict__ Bs)
{
    const int t = threadIdx.x, lane = t & 63;
    const int wr = (t >> 6) >> 1, wc = (t >> 6) & 1;
    const int fr = lane & 15, fg = lane >> 4;
    const int rb = t >> 1, kb = (t & 1) * 16;

    f32x4 acc[2][4] = {};
    for (int k0 = 0; k0 < K; k0 += 32) {
        const _Float16* p = Bt + (size_t)rb * K + k0 + kb;
        const half8 v0 = *reinterpret_cast<const half8*>(p);
        const half8 v1 = *reinterpret_cast<const half8*>(p + 8);
        *reinterpret_cast<half8*>(&Bs[rb * LDK + kb])     = v0;
        *reinterpret_cast<half8*>(&Bs[rb * LDK + kb + 8]) = v1;
        __syncthreads();

        half8 a[2], bfr[4];
#pragma unroll
        for (int i = 0; i < 2; ++i)
            a[i] = *reinterpret_cast<const half8*>(&actA[(wr * 32 + i * 16 + fr) * lda + k0 + fg * 8]);
#pragma unroll
        for (int j = 0; j < 4; ++j)
            bfr[j] = *reinterpret_cast<const half8*>(&Bs[(wc * 64 + j * 16 + fr) * LDK + fg * 8]);
#pragma unroll
        for (int i = 0; i < 2; ++i)
#pragma unroll
            for (int j = 0; j < 4; ++j)
                acc[i][j] = __builtin_amdgcn_mfma_f32_16x16x32_f16(a[i], bfr[j], acc[i][j], 0, 0, 0);
        __syncthreads();
    }
#pragma unroll
    for (int j = 0; j < 4; ++j) {
        const int gnl = wc * 64 + j * 16 + fr;
        const float bv = bias[gnl];
#pragma unroll
        for (int i = 0; i < 2; ++i)
#pragma unroll
            for (int rr = 0; rr < 4; ++rr) {
                float v = acc[i][j][rr] + bv;
                if (RELU) v = fmaxf(v, 0.f);
                actO[(wr * 32 + i * 16 + fg * 4 + rr) * ldo + oc0 + gnl] = (_Float16)v;
            }
    }
    __syncthreads();
}

// ---------------------------------------------------------------------------
// phase5: blocks [0,EBLK) scatter + CSR-ordered ea2; rest run fused node MLP.
// ---------------------------------------------------------------------------
__global__ __launch_bounds__(256)
void phase5_kernel(const int* __restrict__ ei, const int* __restrict__ offs,
                   int* __restrict__ cur, const float* __restrict__ ea,
                   int* __restrict__ csr_src, unsigned* __restrict__ ea2,
                   const float* __restrict__ G,
                   const _Float16* __restrict__ W1, const float* __restrict__ b1,
                   const _Float16* __restrict__ W2, const float* __restrict__ b2,
                   const _Float16* __restrict__ W3, const float* __restrict__ b3,
                   _Float16* __restrict__ outf, int M)
{
    __shared__ __attribute__((aligned(16))) _Float16 AA[64 * LDA];
    __shared__ __attribute__((aligned(16))) _Float16 AB[64 * LDA];
    __shared__ __attribute__((aligned(16))) _Float16 Bs[128 * LDK];

    const int t = threadIdx.x;
    if (blockIdx.x < EBLK) {
        const int e = blockIdx.x * 256 + t;
        if (e >= NE) return;
        const int d = ei[NE + e];
        const int p = offs[d] + atomicAdd(&cur[d], 1);
        csr_src[p] = ei[e];
        const float* src = ea + (size_t)e * 21;
        unsigned* dst = ea2 + (size_t)p * 21;
#pragma unroll
        for (int q = 0; q < 21; ++q) {
            const __half2 h = __floats2half2_rn(src[q], src[q]);
            dst[q] = __builtin_bit_cast(unsigned, h);
        }
        return;
    }

    const int m0 = (blockIdx.x - EBLK) << 6;
    {
        const int r  = t >> 2;
        const int c0 = (t & 3) * 16;
        const int gm = m0 + r;
#pragma unroll
        for (int h = 0; h < 2; ++h) {
            float4 v0 = make_float4(0.f, 0.f, 0.f, 0.f), v1 = v0;
            if (gm < M) {
                v0 = *reinterpret_cast<const float4*>(G + (size_t)gm * 64 + c0 + h * 8);
                v1 = *reinterpret_cast<const float4*>(G + (size_t)gm * 64 + c0 + h * 8 + 4);
            }
            half8 hv;
            hv[0] = (_Float16)v0.x; hv[1] = (_Float16)v0.y;
            hv[2] = (_Float16)v0.z; hv[3] = (_Float16)v0.w;
            hv[4] = (_Float16)v1.x; hv[5] = (_Float16)v1.y;
            hv[6] = (_Float16)v1.z; hv[7] = (_Float16)v1.w;
            *reinterpret_cast<half8*>(&AA[r * LDA + c0 + h * 8]) = hv;
        }
    }
    __syncthreads();

    layer_l2l<true>(AA, LDA, 64,  W1, b1, AB, LDA, 0, Bs);
    layer_l2l<true>(AB, LDA, 128, W2, b2, AA, LDA, 0, Bs);
    layer_l2l<true>(AA, LDA, 128, W3, b3, AB, LDA, 0, Bs);

    {
        const int r  = t >> 2;
        const int c0 = (t & 3) * 32;
        const int gm = m0 + r;
        if (gm < M) {
#pragma unroll
            for (int x = 0; x < 32; x += 8)
                *reinterpret_cast<half8*>(outf + (size_t)gm * 128 + c0 + x) =
                    *reinterpret_cast<const half8*>(&AB[r * LDA + c0 + x]);
        }
    }
}

// ---------------------------------------------------------------------------
// kqvs v1 (restored from R11): 256 threads, stage act once, loop 4 weight sets.
// k and q pre-scaled by -log2(e) for the exp2 gate path.
// ---------------------------------------------------------------------------
__global__ __launch_bounds__(256)
void kqvs_kernel(const _Float16* __restrict__ act,
                 const _Float16* __restrict__ B0, const _Float16* __restrict__ B1,
                 const _Float16* __restrict__ B2, const _Float16* __restrict__ B3,
                 const float* __restrict__ b0, const float* __restrict__ b1,
                 const float* __restrict__ b2, const float* __restrict__ b3,
                 _Float16* __restrict__ ksb, _Float16* __restrict__ qvb, int M)
{
    __shared__ __attribute__((aligned(16))) _Float16 AA[64 * LDA];
    __shared__ __attribute__((aligned(16))) _Float16 Bs[128 * LDK];

    const int t  = threadIdx.x, lane = t & 63;
    const int m0 = blockIdx.x << 6;
    const int wr = (t >> 6) >> 1, wc = (t >> 6) & 1;
    const int fr = lane & 15, fg = lane >> 4;
    const int rb = t >> 1, kb = (t & 1) * 16;

    {
        const int r  = t >> 2;
        const int c0 = (t & 3) * 32;
        const int gm = m0 + r;
#pragma unroll
        for (int x = 0; x < 32; x += 8) {
            half8 v = {0,0,0,0,0,0,0,0};
            if (gm < M) v = *reinterpret_cast<const half8*>(act + (size_t)gm * 128 + c0 + x);
            *reinterpret_cast<half8*>(&AA[r * LDA + c0 + x]) = v;
        }
    }
    __syncthreads();

#pragma unroll
    for (int nb = 0; nb < 4; ++nb) {
        const _Float16* Bt = (nb == 0) ? B0 : (nb == 1) ? B1 : (nb == 2) ? B2 : B3;
        const float*    bt = (nb == 0) ? b0 : (nb == 1) ? b1 : (nb == 2) ? b2 : b3;
        _Float16* dst = (nb < 2) ? ksb : qvb;
        const int sub = (nb & 1) * 2;
        const float scl = (nb == 0 || nb == 2) ? -1.44269504f : 1.0f;   // k', q'

        f32x4 acc[2][4] = {};
        for (int k0 = 0; k0 < 128; k0 += 32) {
            const _Float16* p = Bt + (size_t)rb * 128 + k0 + kb;
            const half8 v0 = *reinterpret_cast<const half8*>(p);
            const half8 v1 = *reinterpret_cast<const half8*>(p + 8);
            *reinterpret_cast<half8*>(&Bs[rb * LDK + kb])     = v0;
            *reinterpret_cast<half8*>(&Bs[rb * LDK + kb + 8]) = v1;
            __syncthreads();

            half8 a[2], b[4];
#pragma unroll
            for (int i = 0; i < 2; ++i)
                a[i] = *reinterpret_cast<const half8*>(&AA[(wr * 32 + i * 16 + fr) * LDA + k0 + fg * 8]);
#pragma unroll
            for (int j = 0; j < 4; ++j)
                b[j] = *reinterpret_cast<const half8*>(&Bs[(wc * 64 + j * 16 + fr) * LDK + fg * 8]);
#pragma unroll
            for (int i = 0; i < 2; ++i)
#pragma unroll
                for (int j = 0; j < 4; ++j)
                    acc[i][j] = __builtin_amdgcn_mfma_f32_16x16x32_f16(a[i], b[j], acc[i][j], 0, 0, 0);
            __syncthreads();
        }
#pragma unroll
        for (int j = 0; j < 4; ++j) {
            const int gnl = wc * 64 + j * 16 + fr;
            const int pos = ((gnl >> 1) << 2) + sub + (gnl & 1);
            const float bv = bt[gnl];
#pragma unroll
            for (int i = 0; i < 2; ++i) {
                const int mbase = m0 + wr * 32 + i * 16 + fg * 4;
#pragma unroll
                for (int rr = 0; rr < 4; ++rr) {
                    const int gm = mbase + rr;
                    if (gm < M)
                        dst[(size_t)gm * 256 + pos] = (_Float16)((acc[i][j][rr] + bv) * scl);
                }
            }
        }
    }
}

// ---------------------------------------------------------------------------
// Fused graph MLP (+colsum)
// ---------------------------------------------------------------------------
__global__ __launch_bounds__(256)
void graph2_kernel(const _Float16* __restrict__ act,
                   const _Float16* __restrict__ Wg1t, const float* __restrict__ bg1,
                   const _Float16* __restrict__ Wg2t, const float* __restrict__ bg2,
                   _Float16* __restrict__ g2f, float* __restrict__ gsum, int M)
{
    __shared__ __attribute__((aligned(16))) _Float16 AA[64 * LDA];
    __shared__ __attribute__((aligned(16))) _Float16 AB[64 * LDA];
    __shared__ __attribute__((aligned(16))) _Float16 Bs[128 * LDK];

    const int t  = threadIdx.x, lane = t & 63;
    const int m0 = blockIdx.x << 6;
    const int wr = (t >> 6) >> 1, wc = (t >> 6) & 1;
    const int fr = lane & 15, fg = lane >> 4;
    const int rb = t >> 1, kb = (t & 1) * 16;

    {
        const int r  = t >> 2;
        const int c0 = (t & 3) * 32;
        const int gm = m0 + r;
#pragma unroll
        for (int x = 0; x < 32; x += 8) {
            half8 v = {0,0,0,0,0,0,0,0};
            if (gm < M) v = *reinterpret_cast<const half8*>(act + (size_t)gm * 128 + c0 + x);
            *reinterpret_cast<half8*>(&AA[r * LDA + c0 + x]) = v;
        }
    }
    __syncthreads();

    layer_l2l<true>(AA, LDA, 128, Wg1t, bg1, AB, LDA, 0, Bs);

    f32x4 acc[2][4] = {};
    for (int k0 = 0; k0 < 128; k0 += 32) {
        const _Float16* p = Wg2t + (size_t)rb * 128 + k0 + kb;
        const half8 v0 = *reinterpret_cast<const half8*>(p);
        const half8 v1 = *reinterpret_cast<const half8*>(p + 8);
        *reinterpret_cast<half8*>(&Bs[rb * LDK + kb])     = v0;
        *reinterpret_cast<half8*>(&Bs[rb * LDK + kb + 8]) = v1;
        __syncthreads();
        half8 a[2], b[4];
#pragma unroll
        for (int i = 0; i < 2; ++i)
            a[i] = *reinterpret_cast<const half8*>(&AB[(wr * 32 + i * 16 + fr) * LDA + k0 + fg * 8]);
#pragma unroll
        for (int j = 0; j < 4; ++j)
            b[j] = *reinterpret_cast<const half8*>(&Bs[(wc * 64 + j * 16 + fr) * LDK + fg * 8]);
#pragma unroll
        for (int i = 0; i < 2; ++i)
#pragma unroll
            for (int j = 0; j < 4; ++j)
                acc[i][j] = __builtin_amdgcn_mfma_f32_16x16x32_f16(a[i], b[j], acc[i][j], 0, 0, 0);
        __syncthreads();
    }
#pragma unroll
    for (int j = 0; j < 4; ++j) {
        const int gn = wc * 64 + j * 16 + fr;
        const float bv = bg2[gn];
        float csum = 0.f;
#pragma unroll
        for (int i = 0; i < 2; ++i) {
            const int mbase = m0 + wr * 32 + i * 16 + fg * 4;
#pragma unroll
            for (int rr = 0; rr < 4; ++rr) {
                const int gm = mbase + rr;
                if (gm < M) {
                    const float v = acc[i][j][rr] + bv;
                    csum += v;
                    g2f[(size_t)gm * 128 + gn] = (_Float16)v;
                }
            }
        }
        csum += __shfl_xor(csum, 16);
        csum += __shfl_xor(csum, 32);
        if (fg == 0) atomicAdd(&gsum[gn], csum);
    }
}

// ---------------------------------------------------------------------------
// Fused head
// ---------------------------------------------------------------------------
__global__ __launch_bounds__(256)
void head3_kernel(const _Float16* __restrict__ g2f,
                  const _Float16* __restrict__ Wl1t,
                  const float* __restrict__ gvec,
                  const _Float16* __restrict__ Wl2t,
                  const float* __restrict__ bl2,
                  const float* __restrict__ wl3,
                  const float* __restrict__ bl3,
                  float* __restrict__ out, int M)
{
    __shared__ __attribute__((aligned(16))) _Float16 AA[64 * LDA];
    __shared__ __attribute__((aligned(16))) _Float16 UB[64 * LDU];
    __shared__ __attribute__((aligned(16))) _Float16 Bs[128 * LDK];
    __shared__ float psum[2][64];

    const int t  = threadIdx.x, lane = t & 63;
    const int m0 = blockIdx.x << 6;
    const int wr = (t >> 6) >> 1, wc = (t >> 6) & 1;
    const int fr = lane & 15, fg = lane >> 4;
    const int rb = t >> 1, kb = (t & 1) * 16;

    {
        const int r  = t >> 2;
        const int c0 = (t & 3) * 32;
        const int gm = m0 + r;
#pragma unroll
        for (int x = 0; x < 32; x += 8) {
            half8 v = {0,0,0,0,0,0,0,0};
            if (gm < M) v = *reinterpret_cast<const half8*>(g2f + (size_t)gm * 128 + c0 + x);
            *reinterpret_cast<half8*>(&AA[r * LDA + c0 + x]) = v;
        }
    }
    __syncthreads();

    layer_l2l<true>(AA, LDA, 128, Wl1t,             gvec,       UB, LDU, 0,   Bs);
    layer_l2l<true>(AA, LDA, 128, Wl1t + 128 * 128, gvec + 128, UB, LDU, 128, Bs);

    f32x4 acc[2][4] = {};
    for (int k0 = 0; k0 < 256; k0 += 32) {
        const _Float16* p = Wl2t + (size_t)rb * 256 + k0 + kb;
        const half8 v0 = *reinterpret_cast<const half8*>(p);
        const half8 v1 = *reinterpret_cast<const half8*>(p + 8);
        *reinterpret_cast<half8*>(&Bs[rb * LDK + kb])     = v0;
        *reinterpret_cast<half8*>(&Bs[rb * LDK + kb + 8]) = v1;
        __syncthreads();
        half8 a[2], b[4];
#pragma unroll
        for (int i = 0; i < 2; ++i)
            a[i] = *reinterpret_cast<const half8*>(&UB[(wr * 32 + i * 16 + fr) * LDU + k0 + fg * 8]);
#pragma unroll
        for (int j = 0; j < 4; ++j)
            b[j] = *reinterpret_cast<const half8*>(&Bs[(wc * 64 + j * 16 + fr) * LDK + fg * 8]);
#pragma unroll
        for (int i = 0; i < 2; ++i)
#pragma unroll
            for (int j = 0; j < 4; ++j)
                acc[i][j] = __builtin_amdgcn_mfma_f32_16x16x32_f16(a[i], b[j], acc[i][j], 0, 0, 0);
        __syncthreads();
    }

    float p[2][4] = {};
#pragma unroll
    for (int j = 0; j < 4; ++j) {
        const int gnl = wc * 64 + j * 16 + fr;
        const float bv = bl2[gnl];
        const float wv = wl3[gnl];
#pragma unroll
        for (int i = 0; i < 2; ++i)
#pragma unroll
            for (int rr = 0; rr < 4; ++rr)
                p[i][rr] += fmaxf(acc[i][j][rr] + bv, 0.f) * wv;
    }
#pragma unroll
    for (int i = 0; i < 2; ++i)
#pragma unroll
        for (int rr = 0; rr < 4; ++rr) {
            float s = p[i][rr];
            s += __shfl_xor(s, 1);
            s += __shfl_xor(s, 2);
            s += __shfl_xor(s, 4);
            s += __shfl_xor(s, 8);
            p[i][rr] = s;
        }
    if (fr == 0) {
#pragma unroll
        for (int i = 0; i < 2; ++i)
#pragma unroll
            for (int rr = 0; rr < 4; ++rr)
                psum[wc][wr * 32 + i * 16 + fg * 4 + rr] = p[i][rr];
    }
    __syncthreads();
    if (t < 64) {
        const int gm = m0 + t;
        if (gm < M) out[gm] = psum[0][t] + psum[1][t] + bl3[0];
    }
}

// ---------------------------------------------------------------------------
// scans
// ---------------------------------------------------------------------------
__global__ __launch_bounds__(SCAN_BS)
void scan1_kernel(const int* __restrict__ deg, int* __restrict__ incl,
                  int* __restrict__ bsum)
{
    __shared__ int sm[SCAN_BS];
    const int t = threadIdx.x;
    const int i = blockIdx.x * SCAN_BS + t;
    sm[t] = (i < NN) ? deg[i] : 0;
    __syncthreads();
    for (int d = 1; d < SCAN_BS; d <<= 1) {
        const int add = (t >= d) ? sm[t - d] : 0;
        __syncthreads();
        sm[t] += add;
        __syncthreads();
    }
    if (i < NN) incl[i] = sm[t];
    if (t == SCAN_BS - 1) bsum[blockIdx.x] = sm[t];
}

__global__ __launch_bounds__(128)
void scan2_kernel(int* __restrict__ bsum)
{
    __shared__ int sm[128];
    const int t = threadIdx.x;
    const int v = (t < SCAN_NB) ? bsum[t] : 0;
    sm[t] = v;
    __syncthreads();
    for (int d = 1; d < 128; d <<= 1) {
        const int add = (t >= d) ? sm[t - d] : 0;
        __syncthreads();
        sm[t] += add;
        __syncthreads();
    }
    if (t < SCAN_NB) bsum[t] = sm[t] - v;
}

__global__ __launch_bounds__(SCAN_BS)
void scan3_kernel(const int* __restrict__ incl, const int* __restrict__ deg,
                  const int* __restrict__ bsum, int* __restrict__ offs)
{
    const int t = threadIdx.x;
    const int i = blockIdx.x * SCAN_BS + t;
    if (i < NN) offs[i] = incl[i] - deg[i] + bsum[blockIdx.x];
    if (i == 0) offs[NN] = NE;
}

// ---------------------------------------------------------------------------
// Conv aggregation: 2 nodes per wave (degree-variance smoothing); lane =
// channel pair {2l, 2l+1}; w2 preload shared across both nodes.
// ---------------------------------------------------------------------------
__global__ __launch_bounds__(256, 8)
void conv_agg_kernel(const int* __restrict__ offs,
                     const int* __restrict__ csr_src,
                     const unsigned* __restrict__ ea2,
                     const float* __restrict__ We,
                     const _Float16* __restrict__ ksb,
                     const _Float16* __restrict__ qvb,
                     _Float16* __restrict__ outh)
{
    const int t     = threadIdx.x;
    const int lane  = t & 63;
    const int nbase = blockIdx.x * 8 + (t >> 6) * 2;
    if (nbase >= NN) return;

    __half2 w2[21];
#pragma unroll
    for (int q = 0; q < 21; ++q) {
        const float2 wq = *reinterpret_cast<const float2*>(&We[q * HH + 2 * lane]);
        w2[q] = __floats2half2_rn(wq.x, wq.y);
    }

    const __half2 one2 = __float2half2_rn(1.f);
    const __half2 cm2  = __float2half2_rn(-2.88539008f);    // -2*log2e

#define GATHER(S) (*reinterpret_cast<const uint2*>(qvb + (size_t)(S) * 256 + lane * 4))

#define EDGE(QV, J) { \
    const __half2* aa_ = reinterpret_cast<const __half2*>(ea2 + (size_t)(J) * 21); \
    __half2 e01_ = __float2half2_rn(0.f); \
    _Pragma("unroll") \
    for (int q_ = 0; q_ < 21; ++q_) e01_ = __hfma2(aa_[q_], w2[q_], e01_); \
    const __half2 q2_ = __builtin_bit_cast(__half2, (QV).x); \
    const __half2 v2_ = __builtin_bit_cast(__half2, (QV).y); \
    const __half2 arg_ = __hadd2(k2, __hfma2(cm2, e01_, q2_)); \
    const __half2 gate_ = h2rcp(__hadd2(one2, h2exp2(arg_))); \
    const __half2 m_ = __hmul2(gate_, __hadd2(v2_, e01_)); \
    acc0 += __low2float(m_); \
    acc1 += __high2float(m_); }

#pragma unroll
    for (int ni = 0; ni < 2; ++ni) {
        const int n = nbase + ni;
        if (n >= NN) break;

        const uint2 ks = *reinterpret_cast<const uint2*>(ksb + (size_t)n * 256 + lane * 4);
        const __half2 k2 = __builtin_bit_cast(__half2, ks.x);   // k' = -log2e * k
        const __half2 s2 = __builtin_bit_cast(__half2, ks.y);

        const int j0 = __builtin_amdgcn_readfirstlane(offs[n]);
        const int j1 = __builtin_amdgcn_readfirstlane(offs[n + 1]);
        float acc0 = 0.f, acc1 = 0.f;

        int j = j0;
        for (; j + 4 <= j1; j += 4) {
            const int sa = csr_src[j],     sb = csr_src[j + 1];
            const int sc = csr_src[j + 2], sd = csr_src[j + 3];
            const uint2 qva = GATHER(sa);
            const uint2 qvb_ = GATHER(sb);
            const uint2 qvc = GATHER(sc);
            const uint2 qvd = GATHER(sd);
            EDGE(qva, j)
            EDGE(qvb_, j + 1)
            EDGE(qvc, j + 2)
            EDGE(qvd, j + 3)
        }
        for (; j < j1; ++j) {
            const int s_ = csr_src[j];
            const uint2 qv = GATHER(s_);
            EDGE(qv, j)
        }

        const float r0 = fmaxf(acc0 + __low2float(s2), 0.f);
        const float r1 = fmaxf(acc1 + __high2float(s2), 0.f);
        const __half2 res = __floats2half2_rn(r0, r1);
        *reinterpret_cast<__half2*>(outh + (size_t)n * HH + 2 * lane) = res;
    }
#undef GATHER
#undef EDGE
}

// ---------------------------------------------------------------------------
__global__ __launch_bounds__(256)
void gvec_kernel(const float* __restrict__ gsum,
                 const float* __restrict__ Wl1,
                 const float* __restrict__ bl1,
                 float* __restrict__ gvec, float invM)
{
    const int j = threadIdx.x;
    float acc = bl1[j];
    for (int k = 0; k < 128; ++k)
        acc += (gsum[k] * invM) * Wl1[(size_t)(128 + k) * 256 + j];
    gvec[j] = acc;
}

// ---------------------------------------------------------------------------
extern "C" void kernel_launch(void* const* d_in, const int* in_sizes, int n_in,
                              void* d_out, int out_size, void* d_ws, size_t ws_size,
                              hipStream_t stream)
{
    const float* G   = (const float*)d_in[0];
    const int*   ei  = (const int*)  d_in[1];
    const float* ea  = (const float*)d_in[2];
    const float* We1 = (const float*)d_in[3];  const float* be1 = (const float*)d_in[4];
    const float* We2 = (const float*)d_in[5];  const float* be2 = (const float*)d_in[6];
    const float* We3 = (const float*)d_in[7];  const float* be3 = (const float*)d_in[8];
    const float* c1_Wk = (const float*)d_in[9];  const float* c1_bk = (const float*)d_in[10];
    const float* c1_Wq = (const float*)d_in[11]; const float* c1_bq = (const float*)d_in[12];
    const float* c1_Wv = (const float*)d_in[13]; const float* c1_bv = (const float*)d_in[14];
    const float* c1_We = (const float*)d_in[15];
    const float* c1_Ws = (const float*)d_in[16]; const float* c1_bs = (const float*)d_in[17];
    const float* c2_Wk = (const float*)d_in[18]; const float* c2_bk = (const float*)d_in[19];
    const float* c2_Wq = (const float*)d_in[20]; const float* c2_bq = (const float*)d_in[21];
    const float* c2_Wv = (const float*)d_in[22]; const float* c2_bv = (const float*)d_in[23];
    const float* c2_We = (const float*)d_in[24];
    const float* c2_Ws = (const float*)d_in[25]; const float* c2_bs = (const float*)d_in[26];
    const float* Wg1 = (const float*)d_in[27]; const float* bg1 = (const float*)d_in[28];
    const float* Wg2 = (const float*)d_in[29]; const float* bg2 = (const float*)d_in[30];
    const float* Wl1 = (const float*)d_in[31]; const float* bl1 = (const float*)d_in[32];
    const float* Wl2 = (const float*)d_in[33]; const float* bl2 = (const float*)d_in[34];
    const float* Wl3 = (const float*)d_in[35]; const float* bl3 = (const float*)d_in[36];

    float* out = (float*)d_out;

    // ---- workspace layout
    char* ws = (char*)d_ws;
    size_t off = 0;
    _Float16* wps  = (_Float16*)(ws + off); off += 270336 * 2;
    _Float16* hA   = (_Float16*)(ws + off); off += (size_t)NN * 128 * 2;
    _Float16* hB   = (_Float16*)(ws + off); off += (size_t)NN * 128 * 2;
    _Float16* ksb  = (_Float16*)(ws + off); off += (size_t)NN * 256 * 2;
    _Float16* qvb  = (_Float16*)(ws + off); off += (size_t)NN * 256 * 2;
    unsigned* ea2  = (unsigned*)(ws + off); off += (size_t)NE * 21 * 4;
    int*      deg  = (int*)     (ws + off); off += (size_t)NN * 4;
    int*      cur  = (int*)     (ws + off); off += (size_t)NN * 4;
    float*    gsum = (float*)   (ws + off); off += 256 * 4;
    float*    gvec = (float*)   (ws + off); off += 256 * 4;
    int*      incl = (int*)     (ws + off); off += (size_t)NN * 4;
    int*      bsum = (int*)     (ws + off); off += 128 * 4;
    int*      offs = (int*)     (ws + off); off += (size_t)(NN + 2) * 4;
    int*      csr_src = (int*)  (ws + off); off += (size_t)NE * 4;

    const int O_We1 = 0,      O_We2 = 8192,   O_We3 = 24576;
    const int O_c1k = 40960,  O_c1s = 57344,  O_c1q = 73728,  O_c1v = 90112;
    const int O_c2k = 106496, O_c2s = 122880, O_c2q = 139264, O_c2v = 155648;
    const int O_Wg1 = 172032, O_Wg2 = 188416, O_Wl1 = 204800, O_Wl2 = 237568;

    const dim3 blk(256);
    const int  MT = (NN + 63) / 64;       // 782
    const int  AGGB = (NN + 7) / 8;       // 6250 (2 nodes/wave)

    // ---- prep (weights transpose + degree histogram) after zeroing counters
    hipMemsetAsync(deg, 0, (size_t)(2 * NN + 256) * 4, stream);
    prep_kernel<<<dim3(480 + EBLK), blk, 0, stream>>>(
        We1, We2, We3, c1_Wk, c1_Ws, c1_Wq, c1_Wv,
        c2_Wk, c2_Ws, c2_Wq, c2_Wv, Wg1, Wg2, Wl1, Wl2, wps, ei, deg);

    scan1_kernel<<<dim3(SCAN_NB), dim3(SCAN_BS), 0, stream>>>(deg, incl, bsum);
    scan2_kernel<<<dim3(1), dim3(128), 0, stream>>>(bsum);
    scan3_kernel<<<dim3(SCAN_NB), dim3(SCAN_BS), 0, stream>>>(incl, deg, bsum, offs);

    // ---- scatter + ea2 + fused node MLP (overlapped in one dispatch)
    phase5_kernel<<<dim3(EBLK + MT), blk, 0, stream>>>(
        ei, offs, cur, ea, csr_src, ea2, G,
        wps + O_We1, be1, wps + O_We2, be2, wps + O_We3, be3, hA, NN);

    // ---- conv1
    kqvs_kernel<<<dim3(MT), blk, 0, stream>>>(hA,
        wps + O_c1k, wps + O_c1s, wps + O_c1q, wps + O_c1v,
        c1_bk, c1_bs, c1_bq, c1_bv, ksb, qvb, NN);
    conv_agg_kernel<<<dim3(AGGB), blk, 0, stream>>>(offs, csr_src, ea2, c1_We,
        ksb, qvb, hB);

    // ---- conv2
    kqvs_kernel<<<dim3(MT), blk, 0, stream>>>(hB,
        wps + O_c2k, wps + O_c2s, wps + O_c2q, wps + O_c2v,
        c2_bk, c2_bs, c2_bq, c2_bv, ksb, qvb, NN);
    conv_agg_kernel<<<dim3(AGGB), blk, 0, stream>>>(offs, csr_src, ea2, c2_We,
        ksb, qvb, hA);

    // ---- graph MLP (+colsum) -> hB
    graph2_kernel<<<dim3(MT), blk, 0, stream>>>(hA,
        wps + O_Wg1, bg1, wps + O_Wg2, bg2, hB, gsum, NN);

    // ---- graph mean -> gvec
    gvec_kernel<<<dim3(1), dim3(256), 0, stream>>>(gsum, Wl1, bl1, gvec, 1.f / NN);

    // ---- head -> out
    head3_kernel<<<dim3(MT), blk, 0, stream>>>(hB,
        wps + O_Wl1, gvec, wps + O_Wl2, bl2, Wl3, bl3, out, NN);
}

// Round 15
// 448.581 us; speedup vs baseline: 1.2939x; 1.0252x over previous
//
#include <hip/hip_runtime.h>
#include <hip/hip_fp16.h>

#define NN 50000
#define NE 800000
#define HH 128
#define SCAN_BS 512
#define SCAN_NB 98
#define LDK 40
#define LDA 136
#define LDU 264
#define EBLK ((NE + 255) / 256)   // 3125

typedef _Float16 half8 __attribute__((ext_vector_type(8)));
typedef float f32x4  __attribute__((ext_vector_type(4)));

// ---------------------------------------------------------------------------
// prep: blocks [0,480) transpose+cast weights; blocks [480, 480+EBLK) histogram.
// ---------------------------------------------------------------------------
__global__ __launch_bounds__(256)
void prep_kernel(const float* __restrict__ s0,  const float* __restrict__ s1,
                 const float* __restrict__ s2,  const float* __restrict__ s3,
                 const float* __restrict__ s4,  const float* __restrict__ s5,
                 const float* __restrict__ s6,  const float* __restrict__ s7,
                 const float* __restrict__ s8,  const float* __restrict__ s9,
                 const float* __restrict__ s10, const float* __restrict__ s11,
                 const float* __restrict__ s12, const float* __restrict__ s13,
                 const float* __restrict__ s14, _Float16* __restrict__ wps,
                 const int* __restrict__ ei, int* __restrict__ deg)
{
    const int b = blockIdx.x;
    if (b >= 480) {
        const int e = (b - 480) * 256 + threadIdx.x;
        if (e < NE) atomicAdd(&deg[ei[NE + e]], 1);
        return;
    }
    const float* srcs[15] = {s0,s1,s2,s3,s4,s5,s6,s7,s8,s9,s10,s11,s12,s13,s14};
    const int Ks[15]   = {64,128,128,128,128,128,128,128,128,128,128,128,128,128,256};
    const int logKs[15]= { 6,  7,  7,  7,  7,  7,  7,  7,  7,  7,  7,  7,  7,  7,  8};
    const int off[15]  = {0,8192,24576,40960,57344,73728,90112,106496,122880,
                          139264,155648,172032,188416,204800,237568};

    const int mi = b >> 5;
    const int bx = b & 31;
    const float* src = srcs[mi];
    const int K = Ks[mi], logK = logKs[mi];
    const int N = (mi == 13) ? 256 : 128;
    _Float16* dst = wps + off[mi];
    const int tot = K * N;
    const int base = (bx * 256 + threadIdx.x) * 4;
    if (base >= tot) return;
    const int n = base >> logK;
    const int k = base & (K - 1);
#pragma unroll
    for (int x = 0; x < 4; ++x)
        dst[(size_t)n * K + k + x] = (_Float16)src[(size_t)(k + x) * N + n];
}

// ---------------------------------------------------------------------------
// LDS->LDS layer
// ---------------------------------------------------------------------------
template<bool RELU>
__device__ __forceinline__ void layer_l2l(
    const _Float16* __restrict__ actA, int lda, int K,
    const _Float16* __restrict__ Bt,
    const float* __restrict__ bias,
    _Float16* __restrict__ actO, int ldo, int oc0,
    _Float16* __restrict__ Bs)
{
    const int t = threadIdx.x, lane = t & 63;
    const int wr = (t >> 6) >> 1, wc = (t >> 6) & 1;
    const int fr = lane & 15, fg = lane >> 4;
    const int rb = t >> 1, kb = (t & 1) * 16;

    f32x4 acc[2][4] = {};
    for (int k0 = 0; k0 < K; k0 += 32) {
        const _Float16* p = Bt + (size_t)rb * K + k0 + kb;
        const half8 v0 = *reinterpret_cast<const half8*>(p);
        const half8 v1 = *reinterpret_cast<const half8*>(p + 8);
        *reinterpret_cast<half8*>(&Bs[rb * LDK + kb])     = v0;
        *reinterpret_cast<half8*>(&Bs[rb * LDK + kb + 8]) = v1;
        __syncthreads();

        half8 a[2], bfr[4];
#pragma unroll
        for (int i = 0; i < 2; ++i)
            a[i] = *reinterpret_cast<const half8*>(&actA[(wr * 32 + i * 16 + fr) * lda + k0 + fg * 8]);
#pragma unroll
        for (int j = 0; j < 4; ++j)
            bfr[j] = *reinterpret_cast<const half8*>(&Bs[(wc * 64 + j * 16 + fr) * LDK + fg * 8]);
#pragma unroll
        for (int i = 0; i < 2; ++i)
#pragma unroll
            for (int j = 0; j < 4; ++j)
                acc[i][j] = __builtin_amdgcn_mfma_f32_16x16x32_f16(a[i], bfr[j], acc[i][j], 0, 0, 0);
        __syncthreads();
    }
#pragma unroll
    for (int j = 0; j < 4; ++j) {
        const int gnl = wc * 64 + j * 16 + fr;
        const float bv = bias[gnl];
#pragma unroll
        for (int i = 0; i < 2; ++i)
#pragma unroll
            for (int rr = 0; rr < 4; ++rr) {
                float v = acc[i][j][rr] + bv;
                if (RELU) v = fmaxf(v, 0.f);
                actO[(wr * 32 + i * 16 + fg * 4 + rr) * ldo + oc0 + gnl] = (_Float16)v;
            }
    }
    __syncthreads();
}

// ---------------------------------------------------------------------------
// phase5: blocks [0,EBLK) scatter + CSR-ordered padded ea2 (24 dwords/edge);
//         rest run fused node MLP.
// ---------------------------------------------------------------------------
__global__ __launch_bounds__(256)
void phase5_kernel(const int* __restrict__ ei, const int* __restrict__ offs,
                   int* __restrict__ cur, const float* __restrict__ ea,
                   int* __restrict__ csr_src, unsigned* __restrict__ ea2,
                   const float* __restrict__ G,
                   const _Float16* __restrict__ W1, const float* __restrict__ b1,
                   const _Float16* __restrict__ W2, const float* __restrict__ b2,
                   const _Float16* __restrict__ W3, const float* __restrict__ b3,
                   _Float16* __restrict__ outf, int M)
{
    __shared__ __attribute__((aligned(16))) _Float16 AA[64 * LDA];
    __shared__ __attribute__((aligned(16))) _Float16 AB[64 * LDA];
    __shared__ __attribute__((aligned(16))) _Float16 Bs[128 * LDK];

    const int t = threadIdx.x;
    if (blockIdx.x < EBLK) {
        const int e = blockIdx.x * 256 + t;
        if (e >= NE) return;
        const int d = ei[NE + e];
        const int p = offs[d] + atomicAdd(&cur[d], 1);
        csr_src[p] = ei[e];
        const float* src = ea + (size_t)e * 21;
        unsigned* dst = ea2 + (size_t)p * 24;
#pragma unroll
        for (int q = 0; q < 21; ++q) {
            const __half2 h = __floats2half2_rn(src[q], src[q]);
            dst[q] = __builtin_bit_cast(unsigned, h);
        }
        dst[21] = 0u; dst[22] = 0u; dst[23] = 0u;
        return;
    }

    const int m0 = (blockIdx.x - EBLK) << 6;
    {
        const int r  = t >> 2;
        const int c0 = (t & 3) * 16;
        const int gm = m0 + r;
#pragma unroll
        for (int h = 0; h < 2; ++h) {
            float4 v0 = make_float4(0.f, 0.f, 0.f, 0.f), v1 = v0;
            if (gm < M) {
                v0 = *reinterpret_cast<const float4*>(G + (size_t)gm * 64 + c0 + h * 8);
                v1 = *reinterpret_cast<const float4*>(G + (size_t)gm * 64 + c0 + h * 8 + 4);
            }
            half8 hv;
            hv[0] = (_Float16)v0.x; hv[1] = (_Float16)v0.y;
            hv[2] = (_Float16)v0.z; hv[3] = (_Float16)v0.w;
            hv[4] = (_Float16)v1.x; hv[5] = (_Float16)v1.y;
            hv[6] = (_Float16)v1.z; hv[7] = (_Float16)v1.w;
            *reinterpret_cast<half8*>(&AA[r * LDA + c0 + h * 8]) = hv;
        }
    }
    __syncthreads();

    layer_l2l<true>(AA, LDA, 64,  W1, b1, AB, LDA, 0, Bs);
    layer_l2l<true>(AB, LDA, 128, W2, b2, AA, LDA, 0, Bs);
    layer_l2l<true>(AA, LDA, 128, W3, b3, AB, LDA, 0, Bs);

    {
        const int r  = t >> 2;
        const int c0 = (t & 3) * 32;
        const int gm = m0 + r;
        if (gm < M) {
#pragma unroll
            for (int x = 0; x < 32; x += 8)
                *reinterpret_cast<half8*>(outf + (size_t)gm * 128 + c0 + x) =
                    *reinterpret_cast<const half8*>(&AB[r * LDA + c0 + x]);
        }
    }
}

// ---------------------------------------------------------------------------
// kqvs v1: 256 threads, stage act once, loop 4 weight sets.
// k and q pre-scaled by -log2(e) for the exp2 gate path.
// ---------------------------------------------------------------------------
__global__ __launch_bounds__(256)
void kqvs_kernel(const _Float16* __restrict__ act,
                 const _Float16* __restrict__ B0, const _Float16* __restrict__ B1,
                 const _Float16* __restrict__ B2, const _Float16* __restrict__ B3,
                 const float* __restrict__ b0, const float* __restrict__ b1,
                 const float* __restrict__ b2, const float* __restrict__ b3,
                 _Float16* __restrict__ ksb, _Float16* __restrict__ qvb, int M)
{
    __shared__ __attribute__((aligned(16))) _Float16 AA[64 * LDA];
    __shared__ __attribute__((aligned(16))) _Float16 Bs[128 * LDK];

    const int t  = threadIdx.x, lane = t & 63;
    const int m0 = blockIdx.x << 6;
    const int wr = (t >> 6) >> 1, wc = (t >> 6) & 1;
    const int fr = lane & 15, fg = lane >> 4;
    const int rb = t >> 1, kb = (t & 1) * 16;

    {
        const int r  = t >> 2;
        const int c0 = (t & 3) * 32;
        const int gm = m0 + r;
#pragma unroll
        for (int x = 0; x < 32; x += 8) {
            half8 v = {0,0,0,0,0,0,0,0};
            if (gm < M) v = *reinterpret_cast<const half8*>(act + (size_t)gm * 128 + c0 + x);
            *reinterpret_cast<half8*>(&AA[r * LDA + c0 + x]) = v;
        }
    }
    __syncthreads();

#pragma unroll
    for (int nb = 0; nb < 4; ++nb) {
        const _Float16* Bt = (nb == 0) ? B0 : (nb == 1) ? B1 : (nb == 2) ? B2 : B3;
        const float*    bt = (nb == 0) ? b0 : (nb == 1) ? b1 : (nb == 2) ? b2 : b3;
        _Float16* dst = (nb < 2) ? ksb : qvb;
        const int sub = (nb & 1) * 2;
        const float scl = (nb == 0 || nb == 2) ? -1.44269504f : 1.0f;   // k', q'

        f32x4 acc[2][4] = {};
        for (int k0 = 0; k0 < 128; k0 += 32) {
            const _Float16* p = Bt + (size_t)rb * 128 + k0 + kb;
            const half8 v0 = *reinterpret_cast<const half8*>(p);
            const half8 v1 = *reinterpret_cast<const half8*>(p + 8);
            *reinterpret_cast<half8*>(&Bs[rb * LDK + kb])     = v0;
            *reinterpret_cast<half8*>(&Bs[rb * LDK + kb + 8]) = v1;
            __syncthreads();

            half8 a[2], b[4];
#pragma unroll
            for (int i = 0; i < 2; ++i)
                a[i] = *reinterpret_cast<const half8*>(&AA[(wr * 32 + i * 16 + fr) * LDA + k0 + fg * 8]);
#pragma unroll
            for (int j = 0; j < 4; ++j)
                b[j] = *reinterpret_cast<const half8*>(&Bs[(wc * 64 + j * 16 + fr) * LDK + fg * 8]);
#pragma unroll
            for (int i = 0; i < 2; ++i)
#pragma unroll
                for (int j = 0; j < 4; ++j)
                    acc[i][j] = __builtin_amdgcn_mfma_f32_16x16x32_f16(a[i], b[j], acc[i][j], 0, 0, 0);
            __syncthreads();
        }
#pragma unroll
        for (int j = 0; j < 4; ++j) {
            const int gnl = wc * 64 + j * 16 + fr;
            const int pos = ((gnl >> 1) << 2) + sub + (gnl & 1);
            const float bv = bt[gnl];
#pragma unroll
            for (int i = 0; i < 2; ++i) {
                const int mbase = m0 + wr * 32 + i * 16 + fg * 4;
#pragma unroll
                for (int rr = 0; rr < 4; ++rr) {
                    const int gm = mbase + rr;
                    if (gm < M)
                        dst[(size_t)gm * 256 + pos] = (_Float16)((acc[i][j][rr] + bv) * scl);
                }
            }
        }
    }
}

// ---------------------------------------------------------------------------
// Fused graph MLP (+colsum)
// ---------------------------------------------------------------------------
__global__ __launch_bounds__(256)
void graph2_kernel(const _Float16* __restrict__ act,
                   const _Float16* __restrict__ Wg1t, const float* __restrict__ bg1,
                   const _Float16* __restrict__ Wg2t, const float* __restrict__ bg2,
                   _Float16* __restrict__ g2f, float* __restrict__ gsum, int M)
{
    __shared__ __attribute__((aligned(16))) _Float16 AA[64 * LDA];
    __shared__ __attribute__((aligned(16))) _Float16 AB[64 * LDA];
    __shared__ __attribute__((aligned(16))) _Float16 Bs[128 * LDK];

    const int t  = threadIdx.x, lane = t & 63;
    const int m0 = blockIdx.x << 6;
    const int wr = (t >> 6) >> 1, wc = (t >> 6) & 1;
    const int fr = lane & 15, fg = lane >> 4;
    const int rb = t >> 1, kb = (t & 1) * 16;

    {
        const int r  = t >> 2;
        const int c0 = (t & 3) * 32;
        const int gm = m0 + r;
#pragma unroll
        for (int x = 0; x < 32; x += 8) {
            half8 v = {0,0,0,0,0,0,0,0};
            if (gm < M) v = *reinterpret_cast<const half8*>(act + (size_t)gm * 128 + c0 + x);
            *reinterpret_cast<half8*>(&AA[r * LDA + c0 + x]) = v;
        }
    }
    __syncthreads();

    layer_l2l<true>(AA, LDA, 128, Wg1t, bg1, AB, LDA, 0, Bs);

    f32x4 acc[2][4] = {};
    for (int k0 = 0; k0 < 128; k0 += 32) {
        const _Float16* p = Wg2t + (size_t)rb * 128 + k0 + kb;
        const half8 v0 = *reinterpret_cast<const half8*>(p);
        const half8 v1 = *reinterpret_cast<const half8*>(p + 8);
        *reinterpret_cast<half8*>(&Bs[rb * LDK + kb])     = v0;
        *reinterpret_cast<half8*>(&Bs[rb * LDK + kb + 8]) = v1;
        __syncthreads();
        half8 a[2], b[4];
#pragma unroll
        for (int i = 0; i < 2; ++i)
            a[i] = *reinterpret_cast<const half8*>(&AB[(wr * 32 + i * 16 + fr) * LDA + k0 + fg * 8]);
#pragma unroll
        for (int j = 0; j < 4; ++j)
            b[j] = *reinterpret_cast<const half8*>(&Bs[(wc * 64 + j * 16 + fr) * LDK + fg * 8]);
#pragma unroll
        for (int i = 0; i < 2; ++i)
#pragma unroll
            for (int j = 0; j < 4; ++j)
                acc[i][j] = __builtin_amdgcn_mfma_f32_16x16x32_f16(a[i], b[j], acc[i][j], 0, 0, 0);
        __syncthreads();
    }
#pragma unroll
    for (int j = 0; j < 4; ++j) {
        const int gn = wc * 64 + j * 16 + fr;
        const float bv = bg2[gn];
        float csum = 0.f;
#pragma unroll
        for (int i = 0; i < 2; ++i) {
            const int mbase = m0 + wr * 32 + i * 16 + fg * 4;
#pragma unroll
            for (int rr = 0; rr < 4; ++rr) {
                const int gm = mbase + rr;
                if (gm < M) {
                    const float v = acc[i][j][rr] + bv;
                    csum += v;
                    g2f[(size_t)gm * 128 + gn] = (_Float16)v;
                }
            }
        }
        csum += __shfl_xor(csum, 16);
        csum += __shfl_xor(csum, 32);
        if (fg == 0) atomicAdd(&gsum[gn], csum);
    }
}

// ---------------------------------------------------------------------------
// Fused head
// ---------------------------------------------------------------------------
__global__ __launch_bounds__(256)
void head3_kernel(const _Float16* __restrict__ g2f,
                  const _Float16* __restrict__ Wl1t,
                  const float* __restrict__ gvec,
                  const _Float16* __restrict__ Wl2t,
                  const float* __restrict__ bl2,
                  const float* __restrict__ wl3,
                  const float* __restrict__ bl3,
                  float* __restrict__ out, int M)
{
    __shared__ __attribute__((aligned(16))) _Float16 AA[64 * LDA];
    __shared__ __attribute__((aligned(16))) _Float16 UB[64 * LDU];
    __shared__ __attribute__((aligned(16))) _Float16 Bs[128 * LDK];
    __shared__ float psum[2][64];

    const int t  = threadIdx.x, lane = t & 63;
    const int m0 = blockIdx.x << 6;
    const int wr = (t >> 6) >> 1, wc = (t >> 6) & 1;
    const int fr = lane & 15, fg = lane >> 4;
    const int rb = t >> 1, kb = (t & 1) * 16;

    {
        const int r  = t >> 2;
        const int c0 = (t & 3) * 32;
        const int gm = m0 + r;
#pragma unroll
        for (int x = 0; x < 32; x += 8) {
            half8 v = {0,0,0,0,0,0,0,0};
            if (gm < M) v = *reinterpret_cast<const half8*>(g2f + (size_t)gm * 128 + c0 + x);
            *reinterpret_cast<half8*>(&AA[r * LDA + c0 + x]) = v;
        }
    }
    __syncthreads();

    layer_l2l<true>(AA, LDA, 128, Wl1t,             gvec,       UB, LDU, 0,   Bs);
    layer_l2l<true>(AA, LDA, 128, Wl1t + 128 * 128, gvec + 128, UB, LDU, 128, Bs);

    f32x4 acc[2][4] = {};
    for (int k0 = 0; k0 < 256; k0 += 32) {
        const _Float16* p = Wl2t + (size_t)rb * 256 + k0 + kb;
        const half8 v0 = *reinterpret_cast<const half8*>(p);
        const half8 v1 = *reinterpret_cast<const half8*>(p + 8);
        *reinterpret_cast<half8*>(&Bs[rb * LDK + kb])     = v0;
        *reinterpret_cast<half8*>(&Bs[rb * LDK + kb + 8]) = v1;
        __syncthreads();
        half8 a[2], b[4];
#pragma unroll
        for (int i = 0; i < 2; ++i)
            a[i] = *reinterpret_cast<const half8*>(&UB[(wr * 32 + i * 16 + fr) * LDU + k0 + fg * 8]);
#pragma unroll
        for (int j = 0; j < 4; ++j)
            b[j] = *reinterpret_cast<const half8*>(&Bs[(wc * 64 + j * 16 + fr) * LDK + fg * 8]);
#pragma unroll
        for (int i = 0; i < 2; ++i)
#pragma unroll
            for (int j = 0; j < 4; ++j)
                acc[i][j] = __builtin_amdgcn_mfma_f32_16x16x32_f16(a[i], b[j], acc[i][j], 0, 0, 0);
        __syncthreads();
    }

    float p[2][4] = {};
#pragma unroll
    for (int j = 0; j < 4; ++j) {
        const int gnl = wc * 64 + j * 16 + fr;
        const float bv = bl2[gnl];
        const float wv = wl3[gnl];
#pragma unroll
        for (int i = 0; i < 2; ++i)
#pragma unroll
            for (int rr = 0; rr < 4; ++rr)
                p[i][rr] += fmaxf(acc[i][j][rr] + bv, 0.f) * wv;
    }
#pragma unroll
    for (int i = 0; i < 2; ++i)
#pragma unroll
        for (int rr = 0; rr < 4; ++rr) {
            float s = p[i][rr];
            s += __shfl_xor(s, 1);
            s += __shfl_xor(s, 2);
            s += __shfl_xor(s, 4);
            s += __shfl_xor(s, 8);
            p[i][rr] = s;
        }
    if (fr == 0) {
#pragma unroll
        for (int i = 0; i < 2; ++i)
#pragma unroll
            for (int rr = 0; rr < 4; ++rr)
                psum[wc][wr * 32 + i * 16 + fg * 4 + rr] = p[i][rr];
    }
    __syncthreads();
    if (t < 64) {
        const int gm = m0 + t;
        if (gm < M) out[gm] = psum[0][t] + psum[1][t] + bl3[0];
    }
}

// ---------------------------------------------------------------------------
// scans
// ---------------------------------------------------------------------------
__global__ __launch_bounds__(SCAN_BS)
void scan1_kernel(const int* __restrict__ deg, int* __restrict__ incl,
                  int* __restrict__ bsum)
{
    __shared__ int sm[SCAN_BS];
    const int t = threadIdx.x;
    const int i = blockIdx.x * SCAN_BS + t;
    sm[t] = (i < NN) ? deg[i] : 0;
    __syncthreads();
    for (int d = 1; d < SCAN_BS; d <<= 1) {
        const int add = (t >= d) ? sm[t - d] : 0;
        __syncthreads();
        sm[t] += add;
        __syncthreads();
    }
    if (i < NN) incl[i] = sm[t];
    if (t == SCAN_BS - 1) bsum[blockIdx.x] = sm[t];
}

__global__ __launch_bounds__(128)
void scan2_kernel(int* __restrict__ bsum)
{
    __shared__ int sm[128];
    const int t = threadIdx.x;
    const int v = (t < SCAN_NB) ? bsum[t] : 0;
    sm[t] = v;
    __syncthreads();
    for (int d = 1; d < 128; d <<= 1) {
        const int add = (t >= d) ? sm[t - d] : 0;
        __syncthreads();
        sm[t] += add;
        __syncthreads();
    }
    if (t < SCAN_NB) bsum[t] = sm[t] - v;
}

__global__ __launch_bounds__(SCAN_BS)
void scan3_kernel(const int* __restrict__ incl, const int* __restrict__ deg,
                  const int* __restrict__ bsum, int* __restrict__ offs)
{
    const int t = threadIdx.x;
    const int i = blockIdx.x * SCAN_BS + t;
    if (i < NN) offs[i] = incl[i] - deg[i] + bsum[blockIdx.x];
    if (i == 0) offs[NN] = NE;
}

// ---------------------------------------------------------------------------
// Conv aggregation: 1 node/wave (R11 structure); padded ea2 read as 6 uint4
// (uniform address -> s_load_dwordx4; hfma2 takes the word as SGPR operand).
// ---------------------------------------------------------------------------
__global__ __launch_bounds__(256, 8)
void conv_agg_kernel(const int* __restrict__ offs,
                     const int* __restrict__ csr_src,
                     const unsigned* __restrict__ ea2,
                     const float* __restrict__ We,
                     const _Float16* __restrict__ ksb,
                     const _Float16* __restrict__ qvb,
                     _Float16* __restrict__ outh)
{
    const int t    = threadIdx.x;
    const int lane = t & 63;
    const int n    = blockIdx.x * 4 + (t >> 6);
    if (n >= NN) return;

    __half2 w2[21];
#pragma unroll
    for (int q = 0; q < 21; ++q) {
        const float2 wq = *reinterpret_cast<const float2*>(&We[q * HH + 2 * lane]);
        w2[q] = __floats2half2_rn(wq.x, wq.y);
    }

    const uint2 ks = *reinterpret_cast<const uint2*>(ksb + (size_t)n * 256 + lane * 4);
    const __half2 k2 = __builtin_bit_cast(__half2, ks.x);   // k' = -log2e * k
    const __half2 s2 = __builtin_bit_cast(__half2, ks.y);
    const __half2 one2 = __float2half2_rn(1.f);
    const __half2 cm2  = __float2half2_rn(-2.88539008f);    // -2*log2e

    const int j0 = __builtin_amdgcn_readfirstlane(offs[n]);
    const int j1 = __builtin_amdgcn_readfirstlane(offs[n + 1]);
    float acc0 = 0.f, acc1 = 0.f;

#define GATHER(S) (*reinterpret_cast<const uint2*>(qvb + (size_t)(S) * 256 + lane * 4))

#define EDGE(QV, J) { \
    const uint4* ap_ = reinterpret_cast<const uint4*>(ea2 + (size_t)(J) * 24); \
    uint4 ub0_ = ap_[0], ub1_ = ap_[1], ub2_ = ap_[2], ub3_ = ap_[3], ub4_ = ap_[4]; \
    unsigned aw_[21] = {ub0_.x, ub0_.y, ub0_.z, ub0_.w, \
                        ub1_.x, ub1_.y, ub1_.z, ub1_.w, \
                        ub2_.x, ub2_.y, ub2_.z, ub2_.w, \
                        ub3_.x, ub3_.y, ub3_.z, ub3_.w, \
                        ub4_.x, ub4_.y, ub4_.z, ub4_.w, \
                        reinterpret_cast<const unsigned*>(ap_)[20]}; \
    __half2 e01_ = __float2half2_rn(0.f); \
    _Pragma("unroll") \
    for (int q_ = 0; q_ < 21; ++q_) e01_ = __hfma2(__builtin_bit_cast(__half2, aw_[q_]), w2[q_], e01_); \
    const __half2 q2_ = __builtin_bit_cast(__half2, (QV).x); \
    const __half2 v2_ = __builtin_bit_cast(__half2, (QV).y); \
    const __half2 arg_ = __hadd2(k2, __hfma2(cm2, e01_, q2_)); \
    const __half2 gate_ = h2rcp(__hadd2(one2, h2exp2(arg_))); \
    const __half2 m_ = __hmul2(gate_, __hadd2(v2_, e01_)); \
    acc0 += __low2float(m_); \
    acc1 += __high2float(m_); }

    int j = j0;
    for (; j + 4 <= j1; j += 4) {
        const int sa = csr_src[j],     sb = csr_src[j + 1];
        const int sc = csr_src[j + 2], sd = csr_src[j + 3];
        const uint2 qva = GATHER(sa);
        const uint2 qvb_ = GATHER(sb);
        const uint2 qvc = GATHER(sc);
        const uint2 qvd = GATHER(sd);
        EDGE(qva, j)
        EDGE(qvb_, j + 1)
        EDGE(qvc, j + 2)
        EDGE(qvd, j + 3)
    }
    for (; j < j1; ++j) {
        const int s_ = csr_src[j];
        const uint2 qv = GATHER(s_);
        EDGE(qv, j)
    }
#undef GATHER
#undef EDGE

    const float r0 = fmaxf(acc0 + __low2float(s2), 0.f);
    const float r1 = fmaxf(acc1 + __high2float(s2), 0.f);
    const __half2 res = __floats2half2_rn(r0, r1);
    *reinterpret_cast<__half2*>(outh + (size_t)n * HH + 2 * lane) = res;
}

// ---------------------------------------------------------------------------
__global__ __launch_bounds__(256)
void gvec_kernel(const float* __restrict__ gsum,
                 const float* __restrict__ Wl1,
                 const float* __restrict__ bl1,
                 float* __restrict__ gvec, float invM)
{
    const int j = threadIdx.x;
    float acc = bl1[j];
    for (int k = 0; k < 128; ++k)
        acc += (gsum[k] * invM) * Wl1[(size_t)(128 + k) * 256 + j];
    gvec[j] = acc;
}

// ---------------------------------------------------------------------------
extern "C" void kernel_launch(void* const* d_in, const int* in_sizes, int n_in,
                              void* d_out, int out_size, void* d_ws, size_t ws_size,
                              hipStream_t stream)
{
    const float* G   = (const float*)d_in[0];
    const int*   ei  = (const int*)  d_in[1];
    const float* ea  = (const float*)d_in[2];
    const float* We1 = (const float*)d_in[3];  const float* be1 = (const float*)d_in[4];
    const float* We2 = (const float*)d_in[5];  const float* be2 = (const float*)d_in[6];
    const float* We3 = (const float*)d_in[7];  const float* be3 = (const float*)d_in[8];
    const float* c1_Wk = (const float*)d_in[9];  const float* c1_bk = (const float*)d_in[10];
    const float* c1_Wq = (const float*)d_in[11]; const float* c1_bq = (const float*)d_in[12];
    const float* c1_Wv = (const float*)d_in[13]; const float* c1_bv = (const float*)d_in[14];
    const float* c1_We = (const float*)d_in[15];
    const float* c1_Ws = (const float*)d_in[16]; const float* c1_bs = (const float*)d_in[17];
    const float* c2_Wk = (const float*)d_in[18]; const float* c2_bk = (const float*)d_in[19];
    const float* c2_Wq = (const float*)d_in[20]; const float* c2_bq = (const float*)d_in[21];
    const float* c2_Wv = (const float*)d_in[22]; const float* c2_bv = (const float*)d_in[23];
    const float* c2_We = (const float*)d_in[24];
    const float* c2_Ws = (const float*)d_in[25]; const float* c2_bs = (const float*)d_in[26];
    const float* Wg1 = (const float*)d_in[27]; const float* bg1 = (const float*)d_in[28];
    const float* Wg2 = (const float*)d_in[29]; const float* bg2 = (const float*)d_in[30];
    const float* Wl1 = (const float*)d_in[31]; const float* bl1 = (const float*)d_in[32];
    const float* Wl2 = (const float*)d_in[33]; const float* bl2 = (const float*)d_in[34];
    const float* Wl3 = (const float*)d_in[35]; const float* bl3 = (const float*)d_in[36];

    float* out = (float*)d_out;

    // ---- workspace layout (~165 MB; R7 proved this footprint)
    char* ws = (char*)d_ws;
    size_t off = 0;
    _Float16* wps  = (_Float16*)(ws + off); off += 270336 * 2;
    _Float16* hA   = (_Float16*)(ws + off); off += (size_t)NN * 128 * 2;
    _Float16* hB   = (_Float16*)(ws + off); off += (size_t)NN * 128 * 2;
    _Float16* ksb  = (_Float16*)(ws + off); off += (size_t)NN * 256 * 2;
    _Float16* qvb  = (_Float16*)(ws + off); off += (size_t)NN * 256 * 2;
    unsigned* ea2  = (unsigned*)(ws + off); off += (size_t)NE * 24 * 4;   // 76.8 MB (padded)
    int*      deg  = (int*)     (ws + off); off += (size_t)NN * 4;
    int*      cur  = (int*)     (ws + off); off += (size_t)NN * 4;
    float*    gsum = (float*)   (ws + off); off += 256 * 4;
    float*    gvec = (float*)   (ws + off); off += 256 * 4;
    int*      incl = (int*)     (ws + off); off += (size_t)NN * 4;
    int*      bsum = (int*)     (ws + off); off += 128 * 4;
    int*      offs = (int*)     (ws + off); off += (size_t)(NN + 2) * 4;
    int*      csr_src = (int*)  (ws + off); off += (size_t)NE * 4;

    const int O_We1 = 0,      O_We2 = 8192,   O_We3 = 24576;
    const int O_c1k = 40960,  O_c1s = 57344,  O_c1q = 73728,  O_c1v = 90112;
    const int O_c2k = 106496, O_c2s = 122880, O_c2q = 139264, O_c2v = 155648;
    const int O_Wg1 = 172032, O_Wg2 = 188416, O_Wl1 = 204800, O_Wl2 = 237568;

    const dim3 blk(256);
    const int  MT = (NN + 63) / 64;       // 782
    const int  AGGB = (NN + 3) / 4;       // 12500 (1 node/wave)

    // ---- prep (weights transpose + degree histogram) after zeroing counters
    hipMemsetAsync(deg, 0, (size_t)(2 * NN + 256) * 4, stream);
    prep_kernel<<<dim3(480 + EBLK), blk, 0, stream>>>(
        We1, We2, We3, c1_Wk, c1_Ws, c1_Wq, c1_Wv,
        c2_Wk, c2_Ws, c2_Wq, c2_Wv, Wg1, Wg2, Wl1, Wl2, wps, ei, deg);

    scan1_kernel<<<dim3(SCAN_NB), dim3(SCAN_BS), 0, stream>>>(deg, incl, bsum);
    scan2_kernel<<<dim3(1), dim3(128), 0, stream>>>(bsum);
    scan3_kernel<<<dim3(SCAN_NB), dim3(SCAN_BS), 0, stream>>>(incl, deg, bsum, offs);

    // ---- scatter + ea2 + fused node MLP (overlapped in one dispatch)
    phase5_kernel<<<dim3(EBLK + MT), blk, 0, stream>>>(
        ei, offs, cur, ea, csr_src, ea2, G,
        wps + O_We1, be1, wps + O_We2, be2, wps + O_We3, be3, hA, NN);

    // ---- conv1
    kqvs_kernel<<<dim3(MT), blk, 0, stream>>>(hA,
        wps + O_c1k, wps + O_c1s, wps + O_c1q, wps + O_c1v,
        c1_bk, c1_bs, c1_bq, c1_bv, ksb, qvb, NN);
    conv_agg_kernel<<<dim3(AGGB), blk, 0, stream>>>(offs, csr_src, ea2, c1_We,
        ksb, qvb, hB);

    // ---- conv2
    kqvs_kernel<<<dim3(MT), blk, 0, stream>>>(hB,
        wps + O_c2k, wps + O_c2s, wps + O_c2q, wps + O_c2v,
        c2_bk, c2_bs, c2_bq, c2_bv, ksb, qvb, NN);
    conv_agg_kernel<<<dim3(AGGB), blk, 0, stream>>>(offs, csr_src, ea2, c2_We,
        ksb, qvb, hA);

    // ---- graph MLP (+colsum) -> hB
    graph2_kernel<<<dim3(MT), blk, 0, stream>>>(hA,
        wps + O_Wg1, bg1, wps + O_Wg2, bg2, hB, gsum, NN);

    // ---- graph mean -> gvec
    gvec_kernel<<<dim3(1), dim3(256), 0, stream>>>(gsum, Wl1, bl1, gvec, 1.f / NN);

    // ---- head -> out
    head3_kernel<<<dim3(MT), blk, 0, stream>>>(hB,
        wps + O_Wl1, gvec, wps + O_Wl2, bl2, Wl3, bl3, out, NN);
}

// Round 16
// 442.263 us; speedup vs baseline: 1.3124x; 1.0143x over previous
//
#include <hip/hip_runtime.h>
#include <hip/hip_fp16.h>

#define NN 50000
#define NE 800000
#define HH 128
#define SCAN_BS 512
#define SCAN_NB 98
#define LDK 40
#define LDA 136
#define LDU 264
#define EBLK ((NE + 255) / 256)   // 3125

typedef _Float16 half8 __attribute__((ext_vector_type(8)));
typedef float f32x4  __attribute__((ext_vector_type(4)));

// ---------------------------------------------------------------------------
// prep: blocks [0,480) transpose+cast weights; blocks [480, 480+EBLK) histogram.
// ---------------------------------------------------------------------------
__global__ __launch_bounds__(256)
void prep_kernel(const float* __restrict__ s0,  const float* __restrict__ s1,
                 const float* __restrict__ s2,  const float* __restrict__ s3,
                 const float* __restrict__ s4,  const float* __restrict__ s5,
                 const float* __restrict__ s6,  const float* __restrict__ s7,
                 const float* __restrict__ s8,  const float* __restrict__ s9,
                 const float* __restrict__ s10, const float* __restrict__ s11,
                 const float* __restrict__ s12, const float* __restrict__ s13,
                 const float* __restrict__ s14, _Float16* __restrict__ wps,
                 const int* __restrict__ ei, int* __restrict__ deg)
{
    const int b = blockIdx.x;
    if (b >= 480) {
        const int e = (b - 480) * 256 + threadIdx.x;
        if (e < NE) atomicAdd(&deg[ei[NE + e]], 1);
        return;
    }
    const float* srcs[15] = {s0,s1,s2,s3,s4,s5,s6,s7,s8,s9,s10,s11,s12,s13,s14};
    const int Ks[15]   = {64,128,128,128,128,128,128,128,128,128,128,128,128,128,256};
    const int logKs[15]= { 6,  7,  7,  7,  7,  7,  7,  7,  7,  7,  7,  7,  7,  7,  8};
    const int off[15]  = {0,8192,24576,40960,57344,73728,90112,106496,122880,
                          139264,155648,172032,188416,204800,237568};

    const int mi = b >> 5;
    const int bx = b & 31;
    const float* src = srcs[mi];
    const int K = Ks[mi], logK = logKs[mi];
    const int N = (mi == 13) ? 256 : 128;
    _Float16* dst = wps + off[mi];
    const int tot = K * N;
    const int base = (bx * 256 + threadIdx.x) * 4;
    if (base >= tot) return;
    const int n = base >> logK;
    const int k = base & (K - 1);
#pragma unroll
    for (int x = 0; x < 4; ++x)
        dst[(size_t)n * K + k + x] = (_Float16)src[(size_t)(k + x) * N + n];
}

// ---------------------------------------------------------------------------
// LDS->LDS layer
// ---------------------------------------------------------------------------
template<bool RELU>
__device__ __forceinline__ void layer_l2l(
    const _Float16* __restrict__ actA, int lda, int K,
    const _Float16* __restrict__ Bt,
    const float* __restrict__ bias,
    _Float16* __restrict__ actO, int ldo, int oc0,
    _Float16* __restrict__ Bs)
{
    const int t = threadIdx.x, lane = t & 63;
    const int wr = (t >> 6) >> 1, wc = (t >> 6) & 1;
    const int fr = lane & 15, fg = lane >> 4;
    const int rb = t >> 1, kb = (t & 1) * 16;

    f32x4 acc[2][4] = {};
    for (int k0 = 0; k0 < K; k0 += 32) {
        const _Float16* p = Bt + (size_t)rb * K + k0 + kb;
        const half8 v0 = *reinterpret_cast<const half8*>(p);
        const half8 v1 = *reinterpret_cast<const half8*>(p + 8);
        *reinterpret_cast<half8*>(&Bs[rb * LDK + kb])     = v0;
        *reinterpret_cast<half8*>(&Bs[rb * LDK + kb + 8]) = v1;
        __syncthreads();

        half8 a[2], bfr[4];
#pragma unroll
        for (int i = 0; i < 2; ++i)
            a[i] = *reinterpret_cast<const half8*>(&actA[(wr * 32 + i * 16 + fr) * lda + k0 + fg * 8]);
#pragma unroll
        for (int j = 0; j < 4; ++j)
            bfr[j] = *reinterpret_cast<const half8*>(&Bs[(wc * 64 + j * 16 + fr) * LDK + fg * 8]);
#pragma unroll
        for (int i = 0; i < 2; ++i)
#pragma unroll
            for (int j = 0; j < 4; ++j)
                acc[i][j] = __builtin_amdgcn_mfma_f32_16x16x32_f16(a[i], bfr[j], acc[i][j], 0, 0, 0);
        __syncthreads();
    }
#pragma unroll
    for (int j = 0; j < 4; ++j) {
        const int gnl = wc * 64 + j * 16 + fr;
        const float bv = bias[gnl];
#pragma unroll
        for (int i = 0; i < 2; ++i)
#pragma unroll
            for (int rr = 0; rr < 4; ++rr) {
                float v = acc[i][j][rr] + bv;
                if (RELU) v = fmaxf(v, 0.f);
                actO[(wr * 32 + i * 16 + fg * 4 + rr) * ldo + oc0 + gnl] = (_Float16)v;
            }
    }
    __syncthreads();
}

// ---------------------------------------------------------------------------
// phase5: blocks [0,EBLK) scatter + CSR-ordered padded ea2 (24 dwords/edge);
//         rest run fused node MLP.
// ---------------------------------------------------------------------------
__global__ __launch_bounds__(256)
void phase5_kernel(const int* __restrict__ ei, const int* __restrict__ offs,
                   int* __restrict__ cur, const float* __restrict__ ea,
                   int* __restrict__ csr_src, unsigned* __restrict__ ea2,
                   const float* __restrict__ G,
                   const _Float16* __restrict__ W1, const float* __restrict__ b1,
                   const _Float16* __restrict__ W2, const float* __restrict__ b2,
                   const _Float16* __restrict__ W3, const float* __restrict__ b3,
                   _Float16* __restrict__ outf, int M)
{
    __shared__ __attribute__((aligned(16))) _Float16 AA[64 * LDA];
    __shared__ __attribute__((aligned(16))) _Float16 AB[64 * LDA];
    __shared__ __attribute__((aligned(16))) _Float16 Bs[128 * LDK];

    const int t = threadIdx.x;
    if (blockIdx.x < EBLK) {
        const int e = blockIdx.x * 256 + t;
        if (e >= NE) return;
        const int d = ei[NE + e];
        const int p = offs[d] + atomicAdd(&cur[d], 1);
        csr_src[p] = ei[e];
        const float* src = ea + (size_t)e * 21;
        unsigned* dst = ea2 + (size_t)p * 24;
#pragma unroll
        for (int q = 0; q < 21; ++q) {
            const __half2 h = __floats2half2_rn(src[q], src[q]);
            dst[q] = __builtin_bit_cast(unsigned, h);
        }
        dst[21] = 0u; dst[22] = 0u; dst[23] = 0u;
        return;
    }

    const int m0 = (blockIdx.x - EBLK) << 6;
    {
        const int r  = t >> 2;
        const int c0 = (t & 3) * 16;
        const int gm = m0 + r;
#pragma unroll
        for (int h = 0; h < 2; ++h) {
            float4 v0 = make_float4(0.f, 0.f, 0.f, 0.f), v1 = v0;
            if (gm < M) {
                v0 = *reinterpret_cast<const float4*>(G + (size_t)gm * 64 + c0 + h * 8);
                v1 = *reinterpret_cast<const float4*>(G + (size_t)gm * 64 + c0 + h * 8 + 4);
            }
            half8 hv;
            hv[0] = (_Float16)v0.x; hv[1] = (_Float16)v0.y;
            hv[2] = (_Float16)v0.z; hv[3] = (_Float16)v0.w;
            hv[4] = (_Float16)v1.x; hv[5] = (_Float16)v1.y;
            hv[6] = (_Float16)v1.z; hv[7] = (_Float16)v1.w;
            *reinterpret_cast<half8*>(&AA[r * LDA + c0 + h * 8]) = hv;
        }
    }
    __syncthreads();

    layer_l2l<true>(AA, LDA, 64,  W1, b1, AB, LDA, 0, Bs);
    layer_l2l<true>(AB, LDA, 128, W2, b2, AA, LDA, 0, Bs);
    layer_l2l<true>(AA, LDA, 128, W3, b3, AB, LDA, 0, Bs);

    {
        const int r  = t >> 2;
        const int c0 = (t & 3) * 32;
        const int gm = m0 + r;
        if (gm < M) {
#pragma unroll
            for (int x = 0; x < 32; x += 8)
                *reinterpret_cast<half8*>(outf + (size_t)gm * 128 + c0 + x) =
                    *reinterpret_cast<const half8*>(&AB[r * LDA + c0 + x]);
        }
    }
}

// ---------------------------------------------------------------------------
// kqvs v1: 256 threads, stage act once, loop 4 weight sets.
// k and q pre-scaled by -log2(e) for the exp2 gate path.
// ---------------------------------------------------------------------------
__global__ __launch_bounds__(256)
void kqvs_kernel(const _Float16* __restrict__ act,
                 const _Float16* __restrict__ B0, const _Float16* __restrict__ B1,
                 const _Float16* __restrict__ B2, const _Float16* __restrict__ B3,
                 const float* __restrict__ b0, const float* __restrict__ b1,
                 const float* __restrict__ b2, const float* __restrict__ b3,
                 _Float16* __restrict__ ksb, _Float16* __restrict__ qvb, int M)
{
    __shared__ __attribute__((aligned(16))) _Float16 AA[64 * LDA];
    __shared__ __attribute__((aligned(16))) _Float16 Bs[128 * LDK];

    const int t  = threadIdx.x, lane = t & 63;
    const int m0 = blockIdx.x << 6;
    const int wr = (t >> 6) >> 1, wc = (t >> 6) & 1;
    const int fr = lane & 15, fg = lane >> 4;
    const int rb = t >> 1, kb = (t & 1) * 16;

    {
        const int r  = t >> 2;
        const int c0 = (t & 3) * 32;
        const int gm = m0 + r;
#pragma unroll
        for (int x = 0; x < 32; x += 8) {
            half8 v = {0,0,0,0,0,0,0,0};
            if (gm < M) v = *reinterpret_cast<const half8*>(act + (size_t)gm * 128 + c0 + x);
            *reinterpret_cast<half8*>(&AA[r * LDA + c0 + x]) = v;
        }
    }
    __syncthreads();

#pragma unroll
    for (int nb = 0; nb < 4; ++nb) {
        const _Float16* Bt = (nb == 0) ? B0 : (nb == 1) ? B1 : (nb == 2) ? B2 : B3;
        const float*    bt = (nb == 0) ? b0 : (nb == 1) ? b1 : (nb == 2) ? b2 : b3;
        _Float16* dst = (nb < 2) ? ksb : qvb;
        const int sub = (nb & 1) * 2;
        const float scl = (nb == 0 || nb == 2) ? -1.44269504f : 1.0f;   // k', q'

        f32x4 acc[2][4] = {};
        for (int k0 = 0; k0 < 128; k0 += 32) {
            const _Float16* p = Bt + (size_t)rb * 128 + k0 + kb;
            const half8 v0 = *reinterpret_cast<const half8*>(p);
            const half8 v1 = *reinterpret_cast<const half8*>(p + 8);
            *reinterpret_cast<half8*>(&Bs[rb * LDK + kb])     = v0;
            *reinterpret_cast<half8*>(&Bs[rb * LDK + kb + 8]) = v1;
            __syncthreads();

            half8 a[2], b[4];
#pragma unroll
            for (int i = 0; i < 2; ++i)
                a[i] = *reinterpret_cast<const half8*>(&AA[(wr * 32 + i * 16 + fr) * LDA + k0 + fg * 8]);
#pragma unroll
            for (int j = 0; j < 4; ++j)
                b[j] = *reinterpret_cast<const half8*>(&Bs[(wc * 64 + j * 16 + fr) * LDK + fg * 8]);
#pragma unroll
            for (int i = 0; i < 2; ++i)
#pragma unroll
                for (int j = 0; j < 4; ++j)
                    acc[i][j] = __builtin_amdgcn_mfma_f32_16x16x32_f16(a[i], b[j], acc[i][j], 0, 0, 0);
            __syncthreads();
        }
#pragma unroll
        for (int j = 0; j < 4; ++j) {
            const int gnl = wc * 64 + j * 16 + fr;
            const int pos = ((gnl >> 1) << 2) + sub + (gnl & 1);
            const float bv = bt[gnl];
#pragma unroll
            for (int i = 0; i < 2; ++i) {
                const int mbase = m0 + wr * 32 + i * 16 + fg * 4;
#pragma unroll
                for (int rr = 0; rr < 4; ++rr) {
                    const int gm = mbase + rr;
                    if (gm < M)
                        dst[(size_t)gm * 256 + pos] = (_Float16)((acc[i][j][rr] + bv) * scl);
                }
            }
        }
    }
}

// ---------------------------------------------------------------------------
// Fused graph MLP (+colsum)
// ---------------------------------------------------------------------------
__global__ __launch_bounds__(256)
void graph2_kernel(const _Float16* __restrict__ act,
                   const _Float16* __restrict__ Wg1t, const float* __restrict__ bg1,
                   const _Float16* __restrict__ Wg2t, const float* __restrict__ bg2,
                   _Float16* __restrict__ g2f, float* __restrict__ gsum, int M)
{
    __shared__ __attribute__((aligned(16))) _Float16 AA[64 * LDA];
    __shared__ __attribute__((aligned(16))) _Float16 AB[64 * LDA];
    __shared__ __attribute__((aligned(16))) _Float16 Bs[128 * LDK];

    const int t  = threadIdx.x, lane = t & 63;
    const int m0 = blockIdx.x << 6;
    const int wr = (t >> 6) >> 1, wc = (t >> 6) & 1;
    const int fr = lane & 15, fg = lane >> 4;
    const int rb = t >> 1, kb = (t & 1) * 16;

    {
        const int r  = t >> 2;
        const int c0 = (t & 3) * 32;
        const int gm = m0 + r;
#pragma unroll
        for (int x = 0; x < 32; x += 8) {
            half8 v = {0,0,0,0,0,0,0,0};
            if (gm < M) v = *reinterpret_cast<const half8*>(act + (size_t)gm * 128 + c0 + x);
            *reinterpret_cast<half8*>(&AA[r * LDA + c0 + x]) = v;
        }
    }
    __syncthreads();

    layer_l2l<true>(AA, LDA, 128, Wg1t, bg1, AB, LDA, 0, Bs);

    f32x4 acc[2][4] = {};
    for (int k0 = 0; k0 < 128; k0 += 32) {
        const _Float16* p = Wg2t + (size_t)rb * 128 + k0 + kb;
        const half8 v0 = *reinterpret_cast<const half8*>(p);
        const half8 v1 = *reinterpret_cast<const half8*>(p + 8);
        *reinterpret_cast<half8*>(&Bs[rb * LDK + kb])     = v0;
        *reinterpret_cast<half8*>(&Bs[rb * LDK + kb + 8]) = v1;
        __syncthreads();
        half8 a[2], b[4];
#pragma unroll
        for (int i = 0; i < 2; ++i)
            a[i] = *reinterpret_cast<const half8*>(&AB[(wr * 32 + i * 16 + fr) * LDA + k0 + fg * 8]);
#pragma unroll
        for (int j = 0; j < 4; ++j)
            b[j] = *reinterpret_cast<const half8*>(&Bs[(wc * 64 + j * 16 + fr) * LDK + fg * 8]);
#pragma unroll
        for (int i = 0; i < 2; ++i)
#pragma unroll
            for (int j = 0; j < 4; ++j)
                acc[i][j] = __builtin_amdgcn_mfma_f32_16x16x32_f16(a[i], b[j], acc[i][j], 0, 0, 0);
        __syncthreads();
    }
#pragma unroll
    for (int j = 0; j < 4; ++j) {
        const int gn = wc * 64 + j * 16 + fr;
        const float bv = bg2[gn];
        float csum = 0.f;
#pragma unroll
        for (int i = 0; i < 2; ++i) {
            const int mbase = m0 + wr * 32 + i * 16 + fg * 4;
#pragma unroll
            for (int rr = 0; rr < 4; ++rr) {
                const int gm = mbase + rr;
                if (gm < M) {
                    const float v = acc[i][j][rr] + bv;
                    csum += v;
                    g2f[(size_t)gm * 128 + gn] = (_Float16)v;
                }
            }
        }
        csum += __shfl_xor(csum, 16);
        csum += __shfl_xor(csum, 32);
        if (fg == 0) atomicAdd(&gsum[gn], csum);
    }
}

// ---------------------------------------------------------------------------
// Fused head
// ---------------------------------------------------------------------------
__global__ __launch_bounds__(256)
void head3_kernel(const _Float16* __restrict__ g2f,
                  const _Float16* __restrict__ Wl1t,
                  const float* __restrict__ gvec,
                  const _Float16* __restrict__ Wl2t,
                  const float* __restrict__ bl2,
                  const float* __restrict__ wl3,
                  const float* __restrict__ bl3,
                  float* __restrict__ out, int M)
{
    __shared__ __attribute__((aligned(16))) _Float16 AA[64 * LDA];
    __shared__ __attribute__((aligned(16))) _Float16 UB[64 * LDU];
    __shared__ __attribute__((aligned(16))) _Float16 Bs[128 * LDK];
    __shared__ float psum[2][64];

    const int t  = threadIdx.x, lane = t & 63;
    const int m0 = blockIdx.x << 6;
    const int wr = (t >> 6) >> 1, wc = (t >> 6) & 1;
    const int fr = lane & 15, fg = lane >> 4;
    const int rb = t >> 1, kb = (t & 1) * 16;

    {
        const int r  = t >> 2;
        const int c0 = (t & 3) * 32;
        const int gm = m0 + r;
#pragma unroll
        for (int x = 0; x < 32; x += 8) {
            half8 v = {0,0,0,0,0,0,0,0};
            if (gm < M) v = *reinterpret_cast<const half8*>(g2f + (size_t)gm * 128 + c0 + x);
            *reinterpret_cast<half8*>(&AA[r * LDA + c0 + x]) = v;
        }
    }
    __syncthreads();

    layer_l2l<true>(AA, LDA, 128, Wl1t,             gvec,       UB, LDU, 0,   Bs);
    layer_l2l<true>(AA, LDA, 128, Wl1t + 128 * 128, gvec + 128, UB, LDU, 128, Bs);

    f32x4 acc[2][4] = {};
    for (int k0 = 0; k0 < 256; k0 += 32) {
        const _Float16* p = Wl2t + (size_t)rb * 256 + k0 + kb;
        const half8 v0 = *reinterpret_cast<const half8*>(p);
        const half8 v1 = *reinterpret_cast<const half8*>(p + 8);
        *reinterpret_cast<half8*>(&Bs[rb * LDK + kb])     = v0;
        *reinterpret_cast<half8*>(&Bs[rb * LDK + kb + 8]) = v1;
        __syncthreads();
        half8 a[2], b[4];
#pragma unroll
        for (int i = 0; i < 2; ++i)
            a[i] = *reinterpret_cast<const half8*>(&UB[(wr * 32 + i * 16 + fr) * LDU + k0 + fg * 8]);
#pragma unroll
        for (int j = 0; j < 4; ++j)
            b[j] = *reinterpret_cast<const half8*>(&Bs[(wc * 64 + j * 16 + fr) * LDK + fg * 8]);
#pragma unroll
        for (int i = 0; i < 2; ++i)
#pragma unroll
            for (int j = 0; j < 4; ++j)
                acc[i][j] = __builtin_amdgcn_mfma_f32_16x16x32_f16(a[i], b[j], acc[i][j], 0, 0, 0);
        __syncthreads();
    }

    float p[2][4] = {};
#pragma unroll
    for (int j = 0; j < 4; ++j) {
        const int gnl = wc * 64 + j * 16 + fr;
        const float bv = bl2[gnl];
        const float wv = wl3[gnl];
#pragma unroll
        for (int i = 0; i < 2; ++i)
#pragma unroll
            for (int rr = 0; rr < 4; ++rr)
                p[i][rr] += fmaxf(acc[i][j][rr] + bv, 0.f) * wv;
    }
#pragma unroll
    for (int i = 0; i < 2; ++i)
#pragma unroll
        for (int rr = 0; rr < 4; ++rr) {
            float s = p[i][rr];
            s += __shfl_xor(s, 1);
            s += __shfl_xor(s, 2);
            s += __shfl_xor(s, 4);
            s += __shfl_xor(s, 8);
            p[i][rr] = s;
        }
    if (fr == 0) {
#pragma unroll
        for (int i = 0; i < 2; ++i)
#pragma unroll
            for (int rr = 0; rr < 4; ++rr)
                psum[wc][wr * 32 + i * 16 + fg * 4 + rr] = p[i][rr];
    }
    __syncthreads();
    if (t < 64) {
        const int gm = m0 + t;
        if (gm < M) out[gm] = psum[0][t] + psum[1][t] + bl3[0];
    }
}

// ---------------------------------------------------------------------------
// scans
// ---------------------------------------------------------------------------
__global__ __launch_bounds__(SCAN_BS)
void scan1_kernel(const int* __restrict__ deg, int* __restrict__ incl,
                  int* __restrict__ bsum)
{
    __shared__ int sm[SCAN_BS];
    const int t = threadIdx.x;
    const int i = blockIdx.x * SCAN_BS + t;
    sm[t] = (i < NN) ? deg[i] : 0;
    __syncthreads();
    for (int d = 1; d < SCAN_BS; d <<= 1) {
        const int add = (t >= d) ? sm[t - d] : 0;
        __syncthreads();
        sm[t] += add;
        __syncthreads();
    }
    if (i < NN) incl[i] = sm[t];
    if (t == SCAN_BS - 1) bsum[blockIdx.x] = sm[t];
}

__global__ __launch_bounds__(128)
void scan2_kernel(int* __restrict__ bsum)
{
    __shared__ int sm[128];
    const int t = threadIdx.x;
    const int v = (t < SCAN_NB) ? bsum[t] : 0;
    sm[t] = v;
    __syncthreads();
    for (int d = 1; d < 128; d <<= 1) {
        const int add = (t >= d) ? sm[t - d] : 0;
        __syncthreads();
        sm[t] += add;
        __syncthreads();
    }
    if (t < SCAN_NB) bsum[t] = sm[t] - v;
}

__global__ __launch_bounds__(SCAN_BS)
void scan3_kernel(const int* __restrict__ incl, const int* __restrict__ deg,
                  const int* __restrict__ bsum, int* __restrict__ offs)
{
    const int t = threadIdx.x;
    const int i = blockIdx.x * SCAN_BS + t;
    if (i < NN) offs[i] = incl[i] - deg[i] + bsum[blockIdx.x];
    if (i == 0) offs[NN] = NE;
}

// ---------------------------------------------------------------------------
// Conv aggregation: 1 node/wave; padded ea2 as uint4; e01 via TWO independent
// hfma2 chains (even/odd q) to halve the dependent-latency critical path.
// ---------------------------------------------------------------------------
__global__ __launch_bounds__(256, 8)
void conv_agg_kernel(const int* __restrict__ offs,
                     const int* __restrict__ csr_src,
                     const unsigned* __restrict__ ea2,
                     const float* __restrict__ We,
                     const _Float16* __restrict__ ksb,
                     const _Float16* __restrict__ qvb,
                     _Float16* __restrict__ outh)
{
    const int t    = threadIdx.x;
    const int lane = t & 63;
    const int n    = blockIdx.x * 4 + (t >> 6);
    if (n >= NN) return;

    __half2 w2[21];
#pragma unroll
    for (int q = 0; q < 21; ++q) {
        const float2 wq = *reinterpret_cast<const float2*>(&We[q * HH + 2 * lane]);
        w2[q] = __floats2half2_rn(wq.x, wq.y);
    }

    const uint2 ks = *reinterpret_cast<const uint2*>(ksb + (size_t)n * 256 + lane * 4);
    const __half2 k2 = __builtin_bit_cast(__half2, ks.x);   // k' = -log2e * k
    const __half2 s2 = __builtin_bit_cast(__half2, ks.y);
    const __half2 one2 = __float2half2_rn(1.f);
    const __half2 cm2  = __float2half2_rn(-2.88539008f);    // -2*log2e

    const int j0 = __builtin_amdgcn_readfirstlane(offs[n]);
    const int j1 = __builtin_amdgcn_readfirstlane(offs[n + 1]);
    float acc0 = 0.f, acc1 = 0.f;

#define GATHER(S) (*reinterpret_cast<const uint2*>(qvb + (size_t)(S) * 256 + lane * 4))

#define EDGE(QV, J) { \
    const uint4* ap_ = reinterpret_cast<const uint4*>(ea2 + (size_t)(J) * 24); \
    uint4 ub0_ = ap_[0], ub1_ = ap_[1], ub2_ = ap_[2], ub3_ = ap_[3], ub4_ = ap_[4]; \
    unsigned aw_[21] = {ub0_.x, ub0_.y, ub0_.z, ub0_.w, \
                        ub1_.x, ub1_.y, ub1_.z, ub1_.w, \
                        ub2_.x, ub2_.y, ub2_.z, ub2_.w, \
                        ub3_.x, ub3_.y, ub3_.z, ub3_.w, \
                        ub4_.x, ub4_.y, ub4_.z, ub4_.w, \
                        reinterpret_cast<const unsigned*>(ap_)[20]}; \
    __half2 eA_ = __float2half2_rn(0.f), eB_ = eA_; \
    _Pragma("unroll") \
    for (int q_ = 0; q_ < 20; q_ += 2) { \
        eA_ = __hfma2(__builtin_bit_cast(__half2, aw_[q_]),     w2[q_],     eA_); \
        eB_ = __hfma2(__builtin_bit_cast(__half2, aw_[q_ + 1]), w2[q_ + 1], eB_); \
    } \
    eA_ = __hfma2(__builtin_bit_cast(__half2, aw_[20]), w2[20], eA_); \
    const __half2 e01_ = __hadd2(eA_, eB_); \
    const __half2 q2_ = __builtin_bit_cast(__half2, (QV).x); \
    const __half2 v2_ = __builtin_bit_cast(__half2, (QV).y); \
    const __half2 arg_ = __hadd2(k2, __hfma2(cm2, e01_, q2_)); \
    const __half2 gate_ = h2rcp(__hadd2(one2, h2exp2(arg_))); \
    const __half2 m_ = __hmul2(gate_, __hadd2(v2_, e01_)); \
    acc0 += __low2float(m_); \
    acc1 += __high2float(m_); }

    int j = j0;
    for (; j + 4 <= j1; j += 4) {
        const int sa = csr_src[j],     sb = csr_src[j + 1];
        const int sc = csr_src[j + 2], sd = csr_src[j + 3];
        const uint2 qva = GATHER(sa);
        const uint2 qvb_ = GATHER(sb);
        const uint2 qvc = GATHER(sc);
        const uint2 qvd = GATHER(sd);
        EDGE(qva, j)
        EDGE(qvb_, j + 1)
        EDGE(qvc, j + 2)
        EDGE(qvd, j + 3)
    }
    for (; j < j1; ++j) {
        const int s_ = csr_src[j];
        const uint2 qv = GATHER(s_);
        EDGE(qv, j)
    }
#undef GATHER
#undef EDGE

    const float r0 = fmaxf(acc0 + __low2float(s2), 0.f);
    const float r1 = fmaxf(acc1 + __high2float(s2), 0.f);
    const __half2 res = __floats2half2_rn(r0, r1);
    *reinterpret_cast<__half2*>(outh + (size_t)n * HH + 2 * lane) = res;
}

// ---------------------------------------------------------------------------
__global__ __launch_bounds__(256)
void gvec_kernel(const float* __restrict__ gsum,
                 const float* __restrict__ Wl1,
                 const float* __restrict__ bl1,
                 float* __restrict__ gvec, float invM)
{
    const int j = threadIdx.x;
    float acc = bl1[j];
    for (int k = 0; k < 128; ++k)
        acc += (gsum[k] * invM) * Wl1[(size_t)(128 + k) * 256 + j];
    gvec[j] = acc;
}

// ---------------------------------------------------------------------------
extern "C" void kernel_launch(void* const* d_in, const int* in_sizes, int n_in,
                              void* d_out, int out_size, void* d_ws, size_t ws_size,
                              hipStream_t stream)
{
    const float* G   = (const float*)d_in[0];
    const int*   ei  = (const int*)  d_in[1];
    const float* ea  = (const float*)d_in[2];
    const float* We1 = (const float*)d_in[3];  const float* be1 = (const float*)d_in[4];
    const float* We2 = (const float*)d_in[5];  const float* be2 = (const float*)d_in[6];
    const float* We3 = (const float*)d_in[7];  const float* be3 = (const float*)d_in[8];
    const float* c1_Wk = (const float*)d_in[9];  const float* c1_bk = (const float*)d_in[10];
    const float* c1_Wq = (const float*)d_in[11]; const float* c1_bq = (const float*)d_in[12];
    const float* c1_Wv = (const float*)d_in[13]; const float* c1_bv = (const float*)d_in[14];
    const float* c1_We = (const float*)d_in[15];
    const float* c1_Ws = (const float*)d_in[16]; const float* c1_bs = (const float*)d_in[17];
    const float* c2_Wk = (const float*)d_in[18]; const float* c2_bk = (const float*)d_in[19];
    const float* c2_Wq = (const float*)d_in[20]; const float* c2_bq = (const float*)d_in[21];
    const float* c2_Wv = (const float*)d_in[22]; const float* c2_bv = (const float*)d_in[23];
    const float* c2_We = (const float*)d_in[24];
    const float* c2_Ws = (const float*)d_in[25]; const float* c2_bs = (const float*)d_in[26];
    const float* Wg1 = (const float*)d_in[27]; const float* bg1 = (const float*)d_in[28];
    const float* Wg2 = (const float*)d_in[29]; const float* bg2 = (const float*)d_in[30];
    const float* Wl1 = (const float*)d_in[31]; const float* bl1 = (const float*)d_in[32];
    const float* Wl2 = (const float*)d_in[33]; const float* bl2 = (const float*)d_in[34];
    const float* Wl3 = (const float*)d_in[35]; const float* bl3 = (const float*)d_in[36];

    float* out = (float*)d_out;

    // ---- workspace layout
    char* ws = (char*)d_ws;
    size_t off = 0;
    _Float16* wps  = (_Float16*)(ws + off); off += 270336 * 2;
    _Float16* hA   = (_Float16*)(ws + off); off += (size_t)NN * 128 * 2;
    _Float16* hB   = (_Float16*)(ws + off); off += (size_t)NN * 128 * 2;
    _Float16* ksb  = (_Float16*)(ws + off); off += (size_t)NN * 256 * 2;
    _Float16* qvb  = (_Float16*)(ws + off); off += (size_t)NN * 256 * 2;
    unsigned* ea2  = (unsigned*)(ws + off); off += (size_t)NE * 24 * 4;   // 76.8 MB
    int*      deg  = (int*)     (ws + off); off += (size_t)NN * 4;
    int*      cur  = (int*)     (ws + off); off += (size_t)NN * 4;
    float*    gsum = (float*)   (ws + off); off += 256 * 4;
    float*    gvec = (float*)   (ws + off); off += 256 * 4;
    int*      incl = (int*)     (ws + off); off += (size_t)NN * 4;
    int*      bsum = (int*)     (ws + off); off += 128 * 4;
    int*      offs = (int*)     (ws + off); off += (size_t)(NN + 2) * 4;
    int*      csr_src = (int*)  (ws + off); off += (size_t)NE * 4;

    const int O_We1 = 0,      O_We2 = 8192,   O_We3 = 24576;
    const int O_c1k = 40960,  O_c1s = 57344,  O_c1q = 73728,  O_c1v = 90112;
    const int O_c2k = 106496, O_c2s = 122880, O_c2q = 139264, O_c2v = 155648;
    const int O_Wg1 = 172032, O_Wg2 = 188416, O_Wl1 = 204800, O_Wl2 = 237568;

    const dim3 blk(256);
    const int  MT = (NN + 63) / 64;       // 782
    const int  AGGB = (NN + 3) / 4;       // 12500

    // ---- prep (weights transpose + degree histogram) after zeroing counters
    hipMemsetAsync(deg, 0, (size_t)(2 * NN + 256) * 4, stream);
    prep_kernel<<<dim3(480 + EBLK), blk, 0, stream>>>(
        We1, We2, We3, c1_Wk, c1_Ws, c1_Wq, c1_Wv,
        c2_Wk, c2_Ws, c2_Wq, c2_Wv, Wg1, Wg2, Wl1, Wl2, wps, ei, deg);

    scan1_kernel<<<dim3(SCAN_NB), dim3(SCAN_BS), 0, stream>>>(deg, incl, bsum);
    scan2_kernel<<<dim3(1), dim3(128), 0, stream>>>(bsum);
    scan3_kernel<<<dim3(SCAN_NB), dim3(SCAN_BS), 0, stream>>>(incl, deg, bsum, offs);

    // ---- scatter + ea2 + fused node MLP (overlapped in one dispatch)
    phase5_kernel<<<dim3(EBLK + MT), blk, 0, stream>>>(
        ei, offs, cur, ea, csr_src, ea2, G,
        wps + O_We1, be1, wps + O_We2, be2, wps + O_We3, be3, hA, NN);

    // ---- conv1
    kqvs_kernel<<<dim3(MT), blk, 0, stream>>>(hA,
        wps + O_c1k, wps + O_c1s, wps + O_c1q, wps + O_c1v,
        c1_bk, c1_bs, c1_bq, c1_bv, ksb, qvb, NN);
    conv_agg_kernel<<<dim3(AGGB), blk, 0, stream>>>(offs, csr_src, ea2, c1_We,
        ksb, qvb, hB);

    // ---- conv2
    kqvs_kernel<<<dim3(MT), blk, 0, stream>>>(hB,
        wps + O_c2k, wps + O_c2s, wps + O_c2q, wps + O_c2v,
        c2_bk, c2_bs, c2_bq, c2_bv, ksb, qvb, NN);
    conv_agg_kernel<<<dim3(AGGB), blk, 0, stream>>>(offs, csr_src, ea2, c2_We,
        ksb, qvb, hA);

    // ---- graph MLP (+colsum) -> hB
    graph2_kernel<<<dim3(MT), blk, 0, stream>>>(hA,
        wps + O_Wg1, bg1, wps + O_Wg2, bg2, hB, gsum, NN);

    // ---- graph mean -> gvec
    gvec_kernel<<<dim3(1), dim3(256), 0, stream>>>(gsum, Wl1, bl1, gvec, 1.f / NN);

    // ---- head -> out
    head3_kernel<<<dim3(MT), blk, 0, stream>>>(hB,
        wps + O_Wl1, gvec, wps + O_Wl2, bl2, Wl3, bl3, out, NN);
}